// Round 7
// baseline (1019.988 us; speedup 1.0000x reference)
//
#include <hip/hip_runtime.h>
#include <hip/hip_bf16.h>

#define N_NODES 50000
#define NTILE   3125     // N_NODES/16 exactly
#define NEDGE   800000
#define ETOT    850000

typedef unsigned int u32;
typedef unsigned short u16;
typedef __attribute__((ext_vector_type(8))) short short8;
typedef __attribute__((ext_vector_type(4))) float f32x4;

union FragU { u32 u[4]; short8 s; };

static __device__ __forceinline__ u16 f2b(float f) {
  union { float f; u32 u; } x; x.f = f;
  u32 r = x.u + 0x7fffu + ((x.u >> 16) & 1u);
  return (u16)(r >> 16);
}
static __device__ __forceinline__ u32 pack_bf(float a, float b) {
  return (u32)f2b(a) | ((u32)f2b(b) << 16);
}
static __device__ __forceinline__ u32 cvtpk(float lo, float hi) {
  u32 r; asm("v_cvt_pk_bf16_f32 %0, %1, %2" : "=v"(r) : "v"(lo), "v"(hi));
  return r;
}
static __device__ __forceinline__ float lo_f(u32 p) {
  union { u32 u; float f; } x; x.u = p << 16; return x.f;
}
static __device__ __forceinline__ float hi_f(u32 p) {
  union { u32 u; float f; } x; x.u = p & 0xffff0000u; return x.f;
}
static __device__ __forceinline__ short8 mk4(u32 a, u32 b, u32 c, u32 d) {
  FragU f; f.u[0] = a; f.u[1] = b; f.u[2] = c; f.u[3] = d; return f.s;
}
static __device__ __forceinline__ short8 ldfrag(const u32* p) {
  uint4 v = *(const uint4*)p;
  FragU f; f.u[0] = v.x; f.u[1] = v.y; f.u[2] = v.z; f.u[3] = v.w; return f.s;
}
static __device__ __forceinline__ f32x4 mfma16(short8 a, short8 b, f32x4 c) {
  return __builtin_amdgcn_mfma_f32_16x16x32_bf16(a, b, c, 0, 0, 0);
}
static __device__ __forceinline__ float sigm(float x) { return 1.f / (1.f + __expf(-x)); }
static __device__ __forceinline__ float tanh_f(float x) { return 1.f - 2.f / (__expf(2.f * x) + 1.f); }
static __device__ __forceinline__ float elu_f(float x) { return x > 0.f ? x : __expf(x) - 1.f; }

// shared A/B k-slot bijection: slot(kt, g, j) -> channel pair base
#define CH0(kt, g, j) (((kt) * 2 + ((j) >> 1)) * 16 + (g) * 4 + ((j) & 1) * 2)

// ============ K0: pack seq fp32 -> bf16 tile layout [tile][t][p=dimpair][m] ============
__global__ __launch_bounds__(128) void k_seqpack(const float* __restrict__ seq,
                                                 u32* __restrict__ seqp) {
  __shared__ float sl[16][385];
  int tile = blockIdx.x, tid = threadIdx.x;
  const float4* s4 = (const float4*)seq;
  for (int i = tid; i < 1536; i += 128) {
    int node = i / 96, c4 = i - node * 96;
    float4 v = s4[(size_t)(tile * 16 + node) * 96 + c4];
    sl[node][c4 * 4] = v.x; sl[node][c4 * 4 + 1] = v.y;
    sl[node][c4 * 4 + 2] = v.z; sl[node][c4 * 4 + 3] = v.w;
  }
  __syncthreads();
  u32* op = seqp + (size_t)tile * 3072;
  for (int o = tid; o < 3072; o += 128) {
    int m = o & 15, p = (o >> 4) & 7, t = o >> 7;
    op[o] = cvtpk(sl[m][t * 16 + 2 * p], sl[m][t * 16 + 2 * p + 1]);
  }
}

// ============ K1: MFMA GRU, wave = 16 nodes, tile-coalesced h history ============
__global__ __launch_bounds__(256, 4) void k_gru(
    const u32* __restrict__ seqp, const float* __restrict__ w_ih,
    const float* __restrict__ w_hh, const float* __restrict__ b_ih,
    const float* __restrict__ b_hh, u32* __restrict__ htile,
    float* __restrict__ h_last) {
  __shared__ u32 frg[36 * 256];  // 36KB: 0..11 = gi (w_ih+bias slot), 12+mt*2+kt = w_hh
  int tid = threadIdx.x;
  for (int i = tid; i < 9216; i += 256) {
    int v = i & 3, lane = (i >> 2) & 63, f = i >> 8;
    int g = lane >> 4, mm = lane & 15;
    u32 val = 0u;
    if (f < 12) {
      int gate = f * 16 + mm;
      if (g < 2) {
        int dim = g * 8 + 2 * v;
        val = pack_bf(w_ih[gate * 16 + dim], w_ih[gate * 16 + dim + 1]);
      } else if (g == 2 && v == 0) {
        float bias = b_ih[gate] + (gate < 128 ? b_hh[gate] : 0.f);
        val = pack_bf(bias, 0.f);
      }
    } else {
      int ff = f - 12, mt = ff >> 1, kt = ff & 1;
      int gate = mt * 16 + mm;
      int ch0 = CH0(kt, g, v);
      val = pack_bf(w_hh[gate * 64 + ch0], w_hh[gate * 64 + ch0 + 1]);
    }
    frg[i] = val;
  }
  __syncthreads();
  int w = tid >> 6, lane = tid & 63, g = lane >> 4, m = lane & 15;
  int tile = blockIdx.x * 4 + w;
  if (tile >= NTILE) return;
  int n = tile * 16 + m;
  const f32x4 Z = {0.f, 0.f, 0.f, 0.f};
  float bhn[4][4];
#pragma unroll
  for (int mt = 0; mt < 4; ++mt)
#pragma unroll
    for (int r = 0; r < 4; ++r) bhn[mt][r] = b_hh[128 + mt * 16 + g * 4 + r];
  f32x4 Hc[4] = {Z, Z, Z, Z};
  u32 hb[2][4] = {{0u,0u,0u,0u},{0u,0u,0u,0u}};
  const u32* sp = seqp + (size_t)tile * 3072;
  u32* hp = htile + (size_t)tile * 24 * 512;

  for (int t = 0; t < 24; ++t) {
    u32 sf[4];
    if (g < 2) {
#pragma unroll
      for (int v = 0; v < 4; ++v) sf[v] = sp[(t * 8 + g * 4 + v) * 16 + m];
    } else if (g == 2) { sf[0] = 0x00003f80u; sf[1] = sf[2] = sf[3] = 0u; }
    else { sf[0] = sf[1] = sf[2] = sf[3] = 0u; }
    f32x4 Crz[8], Cgn[4], Cghn[4];
#pragma unroll
    for (int mt = 0; mt < 12; ++mt) {
      short8 a = ldfrag(&frg[(mt * 64 + lane) * 4]);
      f32x4 c = mfma16(a, mk4(sf[0], sf[1], sf[2], sf[3]), Z);
      if (mt < 8) Crz[mt] = c; else Cgn[mt - 8] = c;
    }
#pragma unroll
    for (int mt = 0; mt < 12; ++mt) {
      short8 a = ldfrag(&frg[((12 + mt * 2) * 64 + lane) * 4]);
      short8 b = mk4(hb[0][0], hb[0][1], hb[0][2], hb[0][3]);
      if (mt < 8) Crz[mt] = mfma16(a, b, Crz[mt]);
      else Cghn[mt - 8] = mfma16(a, b, Z);
    }
#pragma unroll
    for (int mt = 0; mt < 12; ++mt) {
      short8 a = ldfrag(&frg[((12 + mt * 2 + 1) * 64 + lane) * 4]);
      short8 b = mk4(hb[1][0], hb[1][1], hb[1][2], hb[1][3]);
      if (mt < 8) Crz[mt] = mfma16(a, b, Crz[mt]);
      else Cghn[mt - 8] = mfma16(a, b, Cghn[mt - 8]);
    }
#pragma unroll
    for (int mt = 0; mt < 4; ++mt)
#pragma unroll
      for (int r = 0; r < 4; ++r) {
        float rr = sigm(Crz[mt][r]);
        float zz = sigm(Crz[mt + 4][r]);
        float nn = tanh_f(Cgn[mt][r] + rr * (Cghn[mt][r] + bhn[mt][r]));
        Hc[mt][r] = nn + zz * (Hc[mt][r] - nn);
      }
#pragma unroll
    for (int kt = 0; kt < 2; ++kt) {
      hb[kt][0] = cvtpk(Hc[2 * kt][0], Hc[2 * kt][1]);
      hb[kt][1] = cvtpk(Hc[2 * kt][2], Hc[2 * kt][3]);
      hb[kt][2] = cvtpk(Hc[2 * kt + 1][0], Hc[2 * kt + 1][1]);
      hb[kt][3] = cvtpk(Hc[2 * kt + 1][2], Hc[2 * kt + 1][3]);
    }
    u32* op = hp + t * 512;
#pragma unroll
    for (int kt = 0; kt < 2; ++kt)
#pragma unroll
      for (int jh = 0; jh < 2; ++jh) {
        int off4 = (kt * 2 + jh) * 4 + g;
        *(uint2*)&op[off4 * 32 + 2 * m] = make_uint2(hb[kt][jh * 2], hb[kt][jh * 2 + 1]);
      }
  }
#pragma unroll
  for (int mt = 0; mt < 4; ++mt)
    *(f32x4*)&h_last[(size_t)n * 64 + mt * 16 + g * 4] = Hc[mt];
}

// ============ K2: fold Wq/Wk/bq + scale into M (64x256) and abk (256) ============
__global__ void k_prep(const float* __restrict__ aw, const float* __restrict__ ab,
                       float* __restrict__ Mall, float* __restrict__ abk) {
  int j = threadIdx.x;
  int h = j >> 6, cp = j & 63;
  if (blockIdx.x < 64) {
    int c = blockIdx.x;
    float acc = 0.f;
    for (int d = 0; d < 16; ++d)
      acc += aw[(h * 16 + d) * 64 + c] * aw[(64 + h * 16 + d) * 64 + cp];
    Mall[c * 256 + j] = 0.25f * acc;
  } else {
    float acc = 0.f;
    for (int d = 0; d < 16; ++d)
      acc += ab[h * 16 + d] * aw[(64 + h * 16 + d) * 64 + cp];
    abk[j] = 0.25f * acc;
  }
}

// ============ K3: fused attention: U-MFMA + online scores/PV + V/out/proj MFMAs ============
__global__ __launch_bounds__(256, 2) void k_attn2(
    const u32* __restrict__ htile, const float* __restrict__ Mall,
    const float* __restrict__ abk, const float* __restrict__ aw,
    const float* __restrict__ ab, const float* __restrict__ out_w,
    const float* __restrict__ out_b, const float* __restrict__ proj_w,
    const float* __restrict__ proj_b, const float* __restrict__ h_last,
    const float* __restrict__ x, u32* __restrict__ xin_b) {
  __shared__ u32 mfrg[32 * 256];  // 32KB Mall frags
  __shared__ u32 vfrg[8 * 256];   // Wv
  __shared__ u32 ofrg[8 * 256];   // out_w
  __shared__ u32 pfrg[8 * 256];   // proj_w
  __shared__ float abks[256];
  __shared__ float smallb[192];   // out_b | proj_b | bv
  int tid = threadIdx.x;
  for (int i = tid; i < 32 * 256; i += 256) {
    int v = i & 3, lane = (i >> 2) & 63, f = i >> 8;
    int kt = f & 1, mt = f >> 1;
    int g = lane >> 4, mm = lane & 15;
    int jj = mt * 16 + mm, ch0 = CH0(kt, g, v);
    mfrg[i] = pack_bf(Mall[ch0 * 256 + jj], Mall[(ch0 + 1) * 256 + jj]);
  }
  for (int i = tid; i < 8 * 256; i += 256) {
    int v = i & 3, lane = (i >> 2) & 63, f = i >> 8;
    int kt = f & 1, mt = f >> 1;
    int g = lane >> 4, mm = lane & 15;
    int vo = mt * 16 + mm, ch0 = CH0(kt, g, v);
    vfrg[i] = pack_bf(aw[(128 + vo) * 64 + ch0], aw[(128 + vo) * 64 + ch0 + 1]);
    ofrg[i] = pack_bf(out_w[vo * 64 + ch0], out_w[vo * 64 + ch0 + 1]);
    pfrg[i] = pack_bf(proj_w[vo * 64 + ch0], proj_w[vo * 64 + ch0 + 1]);
  }
  if (tid < 256) abks[tid] = abk[tid];
  if (tid < 64) {
    smallb[tid] = out_b[tid];
    smallb[64 + tid] = proj_b[tid];
    smallb[128 + tid] = ab[128 + tid];
  }
  __syncthreads();
  int w = tid >> 6, lane = tid & 63, g = lane >> 4, m = lane & 15;
  int tile = blockIdx.x * 4 + w;
  if (tile >= NTILE) return;
  int n = tile * 16 + m;
  const f32x4 Z = {0.f, 0.f, 0.f, 0.f};
  const u32* hp = htile + (size_t)tile * 24 * 512;
  // h23 frags
  u32 h23d[2][4];
#pragma unroll
  for (int kt = 0; kt < 2; ++kt)
#pragma unroll
    for (int jh = 0; jh < 2; ++jh) {
      uint2 v = *(const uint2*)&hp[23 * 512 + ((kt * 2 + jh) * 4 + g) * 32 + 2 * m];
      h23d[kt][jh * 2] = v.x; h23d[kt][jh * 2 + 1] = v.y;
    }
  // U = Mall^T h23 + abk (C-layout: Uc[mt][r] = U[node m][mt*16+g*4+r])
  f32x4 Uc[16];
#pragma unroll
  for (int mt = 0; mt < 16; ++mt) Uc[mt] = *(const f32x4*)&abks[mt * 16 + g * 4];
#pragma unroll
  for (int mt = 0; mt < 16; ++mt)
#pragma unroll
    for (int kt = 0; kt < 2; ++kt)
      Uc[mt] = mfma16(ldfrag(&mfrg[((mt * 2 + kt) * 64 + lane) * 4]),
                      mk4(h23d[kt][0], h23d[kt][1], h23d[kt][2], h23d[kt][3]), Uc[mt]);
  // single pass over t: scores + exp + hbar (no-max softmax: |s| small, bounded)
  float den[4] = {0.f, 0.f, 0.f, 0.f};
  float hbar[4][4][4] = {};
  for (int t = 0; t < 24; ++t) {
    u32 hd[2][4];
#pragma unroll
    for (int kt = 0; kt < 2; ++kt)
#pragma unroll
      for (int jh = 0; jh < 2; ++jh) {
        uint2 v = *(const uint2*)&hp[t * 512 + ((kt * 2 + jh) * 4 + g) * 32 + 2 * m];
        hd[kt][jh * 2] = v.x; hd[kt][jh * 2 + 1] = v.y;
      }
    float hF[4][4];
#pragma unroll
    for (int kt = 0; kt < 2; ++kt)
#pragma unroll
      for (int jh = 0; jh < 2; ++jh)
#pragma unroll
        for (int jl = 0; jl < 2; ++jl) {
          u32 d = hd[kt][jh * 2 + jl];
          hF[kt * 2 + jh][jl * 2] = lo_f(d);
          hF[kt * 2 + jh][jl * 2 + 1] = hi_f(d);
        }
    float s[4];
#pragma unroll
    for (int h = 0; h < 4; ++h) {
      float acc = 0.f;
#pragma unroll
      for (int mt2 = 0; mt2 < 4; ++mt2)
#pragma unroll
        for (int r = 0; r < 4; ++r) acc += Uc[h * 4 + mt2][r] * hF[mt2][r];
      acc += __shfl_xor(acc, 16);
      acc += __shfl_xor(acc, 32);
      s[h] = acc;
    }
#pragma unroll
    for (int h = 0; h < 4; ++h) {
      float p = __expf(s[h]);
      den[h] += p;
#pragma unroll
      for (int mt2 = 0; mt2 < 4; ++mt2)
#pragma unroll
        for (int r = 0; r < 4; ++r) hbar[h][mt2][r] += p * hF[mt2][r];
    }
  }
  // o = Wv hbar / den + bv (per head)
  float oc[4][4];
#pragma unroll
  for (int h = 0; h < 4; ++h) {
    f32x4 C = Z;
#pragma unroll
    for (int kt = 0; kt < 2; ++kt) {
      short8 B = mk4(cvtpk(hbar[h][kt * 2][0], hbar[h][kt * 2][1]),
                     cvtpk(hbar[h][kt * 2][2], hbar[h][kt * 2][3]),
                     cvtpk(hbar[h][kt * 2 + 1][0], hbar[h][kt * 2 + 1][1]),
                     cvtpk(hbar[h][kt * 2 + 1][2], hbar[h][kt * 2 + 1][3]));
      C = mfma16(ldfrag(&vfrg[((h * 2 + kt) * 64 + lane) * 4]), B, C);
    }
    float inv = 1.f / den[h];
    f32x4 bv = *(const f32x4*)&smallb[128 + h * 16 + g * 4];
#pragma unroll
    for (int r = 0; r < 4; ++r) oc[h][r] = C[r] * inv + bv[r];
  }
  // al = out_w o + out_b
  f32x4 alc[4];
#pragma unroll
  for (int mt = 0; mt < 4; ++mt) alc[mt] = *(const f32x4*)&smallb[mt * 16 + g * 4];
#pragma unroll
  for (int kt = 0; kt < 2; ++kt) {
    short8 B = mk4(cvtpk(oc[kt * 2][0], oc[kt * 2][1]),
                   cvtpk(oc[kt * 2][2], oc[kt * 2][3]),
                   cvtpk(oc[kt * 2 + 1][0], oc[kt * 2 + 1][1]),
                   cvtpk(oc[kt * 2 + 1][2], oc[kt * 2 + 1][3]));
#pragma unroll
    for (int mt = 0; mt < 4; ++mt)
      alc[mt] = mfma16(ldfrag(&ofrg[((mt * 2 + kt) * 64 + lane) * 4]), B, alc[mt]);
  }
  // last = h23(fp32) + al ; te = proj_w last + proj_b
  float lc[4][4];
#pragma unroll
  for (int mt = 0; mt < 4; ++mt) {
    f32x4 hl = *(const f32x4*)&h_last[(size_t)n * 64 + mt * 16 + g * 4];
#pragma unroll
    for (int r = 0; r < 4; ++r) lc[mt][r] = hl[r] + alc[mt][r];
  }
  f32x4 tec[4];
#pragma unroll
  for (int mt = 0; mt < 4; ++mt) tec[mt] = *(const f32x4*)&smallb[64 + mt * 16 + g * 4];
#pragma unroll
  for (int kt = 0; kt < 2; ++kt) {
    short8 B = mk4(cvtpk(lc[kt * 2][0], lc[kt * 2][1]),
                   cvtpk(lc[kt * 2][2], lc[kt * 2][3]),
                   cvtpk(lc[kt * 2 + 1][0], lc[kt * 2 + 1][1]),
                   cvtpk(lc[kt * 2 + 1][2], lc[kt * 2 + 1][3]));
#pragma unroll
    for (int mt = 0; mt < 4; ++mt)
      tec[mt] = mfma16(ldfrag(&pfrg[((mt * 2 + kt) * 64 + lane) * 4]), B, tec[mt]);
  }
  // te -> xin_b dw 32..63: per-lane uint2 scatter (8B-aligned, no LDS transpose)
#pragma unroll
  for (int mt = 0; mt < 4; ++mt)
    *(uint2*)&xin_b[(size_t)n * 64 + 32 + mt * 8 + g * 2] =
        make_uint2(cvtpk(tec[mt][0], tec[mt][1]), cvtpk(tec[mt][2], tec[mt][3]));
  // x -> xin_b dw 0..31: direct coalesced conversion (lane (i2,q) owns node i2, block q)
  {
    int i2 = lane >> 2, q = lane & 3;
    int n2 = tile * 16 + i2;
#pragma unroll
    for (int j = 0; j < 2; ++j) {
      float4 x0 = ((const float4*)x)[(size_t)n2 * 16 + q * 4 + 2 * j];
      float4 x1 = ((const float4*)x)[(size_t)n2 * 16 + q * 4 + 2 * j + 1];
      uint4 vv;
      vv.x = cvtpk(x0.x, x0.y); vv.y = cvtpk(x0.z, x0.w);
      vv.z = cvtpk(x1.x, x1.y); vv.w = cvtpk(x1.z, x1.w);
      *(uint4*)&xin_b[(size_t)n2 * 64 + q * 8 + j * 4] = vv;
    }
  }
}

// ============ CSR construction ============
__global__ void k_zero(int* __restrict__ p, int n) {
  int i = blockIdx.x * 256 + threadIdx.x;
  if (i < n) p[i] = 0;
}
__global__ void k_count(const int* __restrict__ ei, int* __restrict__ rowptr) {
  int e = blockIdx.x * 256 + threadIdx.x;
  if (e >= ETOT) return;
  int d = (e < NEDGE) ? ei[NEDGE + e] : (e - NEDGE);
  atomicAdd(&rowptr[d + 1], 1);
}
__global__ void k_scan1(int* __restrict__ data, int* __restrict__ bsum, int n) {
  __shared__ int s[256];
  int i = blockIdx.x * 256 + threadIdx.x;
  s[threadIdx.x] = (i < n) ? data[i] : 0;
  __syncthreads();
  for (int off = 1; off < 256; off <<= 1) {
    int t = (threadIdx.x >= off) ? s[threadIdx.x - off] : 0;
    __syncthreads();
    s[threadIdx.x] += t;
    __syncthreads();
  }
  if (i < n) data[i] = s[threadIdx.x];
  if (threadIdx.x == 255) bsum[blockIdx.x] = s[255];
}
__global__ void k_scan2(int* __restrict__ bsum, int n) {
  __shared__ int s[256];
  int t = threadIdx.x;
  s[t] = (t < n) ? bsum[t] : 0;
  __syncthreads();
  for (int off = 1; off < 256; off <<= 1) {
    int v = (t >= off) ? s[t - off] : 0;
    __syncthreads();
    s[t] += v;
    __syncthreads();
  }
  if (t < n) bsum[t] = s[t];
}
__global__ void k_scan3(int* __restrict__ data, const int* __restrict__ bsum, int n) {
  int i = blockIdx.x * 256 + threadIdx.x;
  if (blockIdx.x > 0 && i < n) data[i] += bsum[blockIdx.x - 1];
}
__global__ void k_copycur(const int* __restrict__ rowptr, int* __restrict__ wcur, int n) {
  int i = blockIdx.x * 256 + threadIdx.x;
  if (i < n) wcur[i] = rowptr[i];
}
__global__ void k_scatter(const int* __restrict__ ei, int* __restrict__ wcur,
                          int* __restrict__ csr_src) {
  int e = blockIdx.x * 256 + threadIdx.x;
  if (e >= ETOT) return;
  int s = (e < NEDGE) ? ei[e] : (e - NEDGE);
  int d = (e < NEDGE) ? ei[NEDGE + e] : (e - NEDGE);
  int pos = atomicAdd(&wcur[d], 1);
  csr_src[pos] = s;
}

// ============ GAT transform (bf16 in/out) + fused attention logits ============
template <int KT>
__global__ __launch_bounds__(256, 2) void k_gat_gemm(
    const u32* __restrict__ A, const float* __restrict__ W,
    const float* __restrict__ at_s, const float* __restrict__ at_d,
    u32* __restrict__ Cout, float* __restrict__ as_out, float* __restrict__ ad_out) {
  __shared__ u32 frg[8 * KT * 256];
  int tid = threadIdx.x;
  int mt0 = blockIdx.y * 8;
  for (int i = tid; i < 8 * KT * 256; i += 256) {
    int v = i & 3, lane = (i >> 2) & 63, f = i >> 8;
    int kt = f % KT, mt = f / KT;
    int g = lane >> 4, mm = lane & 15;
    int o = (mt0 + mt) * 16 + mm;
    int ch0 = CH0(kt, g, v);
    frg[i] = pack_bf(W[ch0 * 256 + o], W[(ch0 + 1) * 256 + o]);
  }
  __syncthreads();
  int w = tid >> 6, lane = tid & 63, g = lane >> 4, m = lane & 15;
  int n0 = blockIdx.x * 128 + w * 32;
  const f32x4 Z = {0.f, 0.f, 0.f, 0.f};
  u32 bfr[2][KT][4];
#pragma unroll
  for (int nt = 0; nt < 2; ++nt) {
    int nn = n0 + nt * 16 + m;
    int nc = nn < N_NODES ? nn : N_NODES - 1;
#pragma unroll
    for (int kt = 0; kt < KT; ++kt)
#pragma unroll
      for (int jh = 0; jh < 2; ++jh) {
        uint2 uv = *(const uint2*)&A[(size_t)nc * (KT * 16) + (kt * 2 + jh) * 8 + g * 2];
        bfr[nt][kt][jh * 2] = uv.x; bfr[nt][kt][jh * 2 + 1] = uv.y;
      }
  }
  float ps[2][2] = {{0.f, 0.f}, {0.f, 0.f}};
  float pd[2][2] = {{0.f, 0.f}, {0.f, 0.f}};
#pragma unroll
  for (int mt = 0; mt < 8; ++mt) {
    f32x4 C[2] = {Z, Z};
#pragma unroll
    for (int kt = 0; kt < KT; ++kt) {
      short8 a = ldfrag(&frg[((mt * KT + kt) * 64 + lane) * 4]);
#pragma unroll
      for (int nt = 0; nt < 2; ++nt)
        C[nt] = mfma16(a, mk4(bfr[nt][kt][0], bfr[nt][kt][1], bfr[nt][kt][2], bfr[nt][kt][3]), C[nt]);
    }
    int j0 = (mt0 + mt) * 16 + g * 4;
    f32x4 as4 = *(const f32x4*)&at_s[j0];
    f32x4 ad4 = *(const f32x4*)&at_d[j0];
#pragma unroll
    for (int nt = 0; nt < 2; ++nt) {
      int nn = n0 + nt * 16 + m;
#pragma unroll
      for (int r = 0; r < 4; ++r) {
        ps[nt][mt >> 2] += C[nt][r] * as4[r];
        pd[nt][mt >> 2] += C[nt][r] * ad4[r];
      }
      if (nn < N_NODES)
        *(uint2*)&Cout[(size_t)nn * 128 + (mt0 + mt) * 8 + g * 2] =
            make_uint2(cvtpk(C[nt][0], C[nt][1]), cvtpk(C[nt][2], C[nt][3]));
    }
  }
#pragma unroll
  for (int nt = 0; nt < 2; ++nt)
#pragma unroll
    for (int hh = 0; hh < 2; ++hh) {
      float s = ps[nt][hh];
      s += __shfl_xor(s, 16); s += __shfl_xor(s, 32);
      float d = pd[nt][hh];
      d += __shfl_xor(d, 16); d += __shfl_xor(d, 32);
      int nn = n0 + nt * 16 + m;
      if (g == 0 && nn < N_NODES) {
        int h = blockIdx.y * 2 + hh;
        as_out[nn * 4 + h] = s;
        ad_out[nn * 4 + h] = d;
      }
    }
}

// ============ GAT1 aggregation: bf16 gather, bf16 out ============
__global__ __launch_bounds__(256) void k_gat_agg1(
    const u32* __restrict__ htb, const float* __restrict__ as_,
    const float* __restrict__ ad_, const int* __restrict__ rowptr,
    const int* __restrict__ csr_src, const float* __restrict__ bias,
    u32* __restrict__ h1b) {
  int w = threadIdx.x >> 6, lane = threadIdx.x & 63;
  int n = blockIdx.x * 4 + w;
  int hg = lane >> 4;
  float adh = ad_[n * 4 + hg];
  int beg = rowptr[n], end = rowptr[n + 1];
  float den = 0.f;
  float4 acc = {0.f, 0.f, 0.f, 0.f};
  for (int e = beg; e < end; ++e) {
    int s = csr_src[e];
    float ev = as_[s * 4 + hg] + adh;
    ev = ev > 0.f ? ev : 0.2f * ev;
    float p = __expf(ev);
    den += p;
    uint2 hv = ((const uint2*)htb)[(size_t)s * 64 + lane];
    acc.x += p * lo_f(hv.x); acc.y += p * hi_f(hv.x);
    acc.z += p * lo_f(hv.y); acc.w += p * hi_f(hv.y);
  }
  float inv = 1.f / den;
  float4 b4 = *(const float4*)&bias[lane * 4];
  float o0 = elu_f(acc.x * inv + b4.x);
  float o1 = elu_f(acc.y * inv + b4.y);
  float o2 = elu_f(acc.z * inv + b4.z);
  float o3 = elu_f(acc.w * inv + b4.w);
  ((uint2*)h1b)[(size_t)n * 64 + lane] = make_uint2(cvtpk(o0, o1), cvtpk(o2, o3));
}

// ============ GAT2 aggregation: bf16 gather, head-mean + elu + fused final linear ============
__global__ __launch_bounds__(256) void k_gat_agg2(
    const u32* __restrict__ htb, const float* __restrict__ as_,
    const float* __restrict__ ad_, const int* __restrict__ rowptr,
    const int* __restrict__ csr_src, const float* __restrict__ bias,
    const float* __restrict__ lin_w, const float* __restrict__ lin_b,
    float* __restrict__ out) {
  int w = threadIdx.x >> 6, lane = threadIdx.x & 63;
  int n = blockIdx.x * 4 + w;
  int hg = lane >> 4, q = lane & 15;
  float adh = ad_[n * 4 + hg];
  int beg = rowptr[n], end = rowptr[n + 1];
  float den = 0.f;
  float4 acc = {0.f, 0.f, 0.f, 0.f};
  for (int e = beg; e < end; ++e) {
    int s = csr_src[e];
    float ev = as_[s * 4 + hg] + adh;
    ev = ev > 0.f ? ev : 0.2f * ev;
    float p = __expf(ev);
    den += p;
    uint2 hv = ((const uint2*)htb)[(size_t)s * 64 + lane];
    acc.x += p * lo_f(hv.x); acc.y += p * hi_f(hv.x);
    acc.z += p * lo_f(hv.y); acc.w += p * hi_f(hv.y);
  }
  float inv = 1.f / den;
  float v0 = acc.x * inv, v1 = acc.y * inv, v2 = acc.z * inv, v3 = acc.w * inv;
  v0 += __shfl_xor(v0, 16); v0 += __shfl_xor(v0, 32);
  v1 += __shfl_xor(v1, 16); v1 += __shfl_xor(v1, 32);
  v2 += __shfl_xor(v2, 16); v2 += __shfl_xor(v2, 32);
  v3 += __shfl_xor(v3, 16); v3 += __shfl_xor(v3, 32);
  float4 b4 = *(const float4*)&bias[q * 4];
  float o0 = elu_f(v0 * 0.25f + b4.x);
  float o1 = elu_f(v1 * 0.25f + b4.y);
  float o2 = elu_f(v2 * 0.25f + b4.z);
  float o3 = elu_f(v3 * 0.25f + b4.w);
  float4 lw = *(const float4*)&lin_w[q * 4];
  float p2 = o0 * lw.x + o1 * lw.y + o2 * lw.z + o3 * lw.w;
  p2 += __shfl_xor(p2, 1); p2 += __shfl_xor(p2, 2);
  p2 += __shfl_xor(p2, 4); p2 += __shfl_xor(p2, 8);
  if (lane == 0) out[n] = p2 + lin_b[0];
}

extern "C" void kernel_launch(void* const* d_in, const int* in_sizes, int n_in,
                              void* d_out, int out_size, void* d_ws, size_t ws_size,
                              hipStream_t stream) {
  const float* x         = (const float*)d_in[0];
  const int*   ei        = (const int*)d_in[1];
  const float* seq       = (const float*)d_in[2];
  const float* gru_w_ih  = (const float*)d_in[3];
  const float* gru_w_hh  = (const float*)d_in[4];
  const float* gru_b_ih  = (const float*)d_in[5];
  const float* gru_b_hh  = (const float*)d_in[6];
  const float* attn_in_w = (const float*)d_in[7];
  const float* attn_in_b = (const float*)d_in[8];
  const float* attn_out_w= (const float*)d_in[9];
  const float* attn_out_b= (const float*)d_in[10];
  const float* proj_w    = (const float*)d_in[11];
  const float* proj_b    = (const float*)d_in[12];
  const float* gat1_w    = (const float*)d_in[13];
  const float* g1as      = (const float*)d_in[14];
  const float* g1ad      = (const float*)d_in[15];
  const float* gat1_b    = (const float*)d_in[16];
  const float* gat2_w    = (const float*)d_in[17];
  const float* g2as      = (const float*)d_in[18];
  const float* g2ad      = (const float*)d_in[19];
  const float* gat2_b    = (const float*)d_in[20];
  const float* lin_w     = (const float*)d_in[21];
  const float* lin_b     = (const float*)d_in[22];
  float* out = (float*)d_out;

  char* p = (char*)d_ws;
  auto alloc = [&](size_t bytes) {
    char* r = p;
    p += (bytes + 255) & ~(size_t)255;
    return r;
  };
  char*  region0 = alloc((size_t)NTILE * 24 * 512 * 4);     // 153.6MB: htile -> htb/h1b
  u32*   seqp    = (u32*)  alloc((size_t)NTILE * 3072 * 4); // 38.4MB
  float* h_last  = (float*)alloc((size_t)N_NODES * 64 * 4); // 12.8MB
  u32*   xin_b   = (u32*)  alloc((size_t)N_NODES * 64 * 4); // 12.8MB
  float* Mall    = (float*)alloc(64 * 256 * 4);
  float* abk     = (float*)alloc(256 * 4);
  float* a1s     = (float*)alloc((size_t)N_NODES * 4 * 4);
  float* a1d     = (float*)alloc((size_t)N_NODES * 4 * 4);
  float* a2s     = (float*)alloc((size_t)N_NODES * 4 * 4);
  float* a2d     = (float*)alloc((size_t)N_NODES * 4 * 4);
  int*   rowptr  = (int*)  alloc((size_t)(N_NODES + 1) * 4);
  int*   wcur    = (int*)  alloc((size_t)N_NODES * 4);
  int*   csr     = (int*)  alloc((size_t)ETOT * 4);
  int*   bsum    = (int*)  alloc(256 * 4);
  u32* htile = (u32*)region0;
  u32* htb   = (u32*)region0;                          // 25.6MB, after htile dead
  u32* h1b   = (u32*)(region0 + ((size_t)32 << 20));   // 25.6MB at +32MB

  // temporal encoder
  k_seqpack<<<NTILE, 128, 0, stream>>>(seq, seqp);
  k_gru<<<(NTILE + 3) / 4, 256, 0, stream>>>(seqp, gru_w_ih, gru_w_hh, gru_b_ih,
                                             gru_b_hh, htile, h_last);
  k_prep<<<65, 256, 0, stream>>>(attn_in_w, attn_in_b, Mall, abk);
  k_attn2<<<(NTILE + 3) / 4, 256, 0, stream>>>(htile, Mall, abk, attn_in_w, attn_in_b,
                                               attn_out_w, attn_out_b, proj_w, proj_b,
                                               h_last, x, xin_b);
  // CSR (dst-sorted), shared by both GAT layers
  k_zero<<<196, 256, 0, stream>>>(rowptr, N_NODES + 1);
  k_count<<<(ETOT + 255) / 256, 256, 0, stream>>>(ei, rowptr);
  k_scan1<<<196, 256, 0, stream>>>(rowptr, bsum, N_NODES + 1);
  k_scan2<<<1, 256, 0, stream>>>(bsum, 196);
  k_scan3<<<196, 256, 0, stream>>>(rowptr, bsum, N_NODES + 1);
  k_copycur<<<(N_NODES + 255) / 256, 256, 0, stream>>>(rowptr, wcur, N_NODES);
  k_scatter<<<(ETOT + 255) / 256, 256, 0, stream>>>(ei, wcur, csr);
  // GAT1 (concat + elu)
  k_gat_gemm<4><<<dim3(391, 2), 256, 0, stream>>>(xin_b, gat1_w, g1as, g1ad,
                                                  htb, a1s, a1d);
  k_gat_agg1<<<12500, 256, 0, stream>>>(htb, a1s, a1d, rowptr, csr, gat1_b, h1b);
  // GAT2 (mean + elu + final linear)
  k_gat_gemm<8><<<dim3(391, 2), 256, 0, stream>>>(h1b, gat2_w, g2as, g2ad,
                                                  htb, a2s, a2d);
  k_gat_agg2<<<12500, 256, 0, stream>>>(htb, a2s, a2d, rowptr, csr, gat2_b,
                                        lin_w, lin_b, out);
}

// Round 8
// 1000.683 us; speedup vs baseline: 1.0193x; 1.0193x over previous
//
#include <hip/hip_runtime.h>
#include <hip/hip_bf16.h>

#define N_NODES 50000
#define NTILE   3125     // N_NODES/16 exactly
#define NEDGE   800000
#define ETOT    850000

typedef unsigned int u32;
typedef unsigned short u16;
typedef __attribute__((ext_vector_type(8))) short short8;
typedef __attribute__((ext_vector_type(4))) float f32x4;

union FragU { u32 u[4]; short8 s; };

static __device__ __forceinline__ u16 f2b(float f) {
  union { float f; u32 u; } x; x.f = f;
  u32 r = x.u + 0x7fffu + ((x.u >> 16) & 1u);
  return (u16)(r >> 16);
}
static __device__ __forceinline__ u32 pack_bf(float a, float b) {
  return (u32)f2b(a) | ((u32)f2b(b) << 16);
}
static __device__ __forceinline__ u32 cvtpk(float lo, float hi) {
  u32 r; asm("v_cvt_pk_bf16_f32 %0, %1, %2" : "=v"(r) : "v"(lo), "v"(hi));
  return r;
}
static __device__ __forceinline__ float lo_f(u32 p) {
  union { u32 u; float f; } x; x.u = p << 16; return x.f;
}
static __device__ __forceinline__ float hi_f(u32 p) {
  union { u32 u; float f; } x; x.u = p & 0xffff0000u; return x.f;
}
static __device__ __forceinline__ short8 mk4(u32 a, u32 b, u32 c, u32 d) {
  FragU f; f.u[0] = a; f.u[1] = b; f.u[2] = c; f.u[3] = d; return f.s;
}
static __device__ __forceinline__ short8 ldfrag(const u32* p) {
  uint4 v = *(const uint4*)p;
  FragU f; f.u[0] = v.x; f.u[1] = v.y; f.u[2] = v.z; f.u[3] = v.w; return f.s;
}
static __device__ __forceinline__ f32x4 mfma16(short8 a, short8 b, f32x4 c) {
  return __builtin_amdgcn_mfma_f32_16x16x32_bf16(a, b, c, 0, 0, 0);
}
static __device__ __forceinline__ float sigm(float x) { return 1.f / (1.f + __expf(-x)); }
static __device__ __forceinline__ float tanh_f(float x) { return 1.f - 2.f / (__expf(2.f * x) + 1.f); }
static __device__ __forceinline__ float elu_f(float x) { return x > 0.f ? x : __expf(x) - 1.f; }

// shared A/B k-slot bijection: slot(kt, g, j) -> channel pair base
#define CH0(kt, g, j) (((kt) * 2 + ((j) >> 1)) * 16 + (g) * 4 + ((j) & 1) * 2)

// ============ K0: pack seq fp32 -> bf16 tile layout [tile][t][p=dimpair][m] ============
__global__ __launch_bounds__(128) void k_seqpack(const float* __restrict__ seq,
                                                 u32* __restrict__ seqp) {
  __shared__ float sl[16][385];
  int tile = blockIdx.x, tid = threadIdx.x;
  const float4* s4 = (const float4*)seq;
  for (int i = tid; i < 1536; i += 128) {
    int node = i / 96, c4 = i - node * 96;
    float4 v = s4[(size_t)(tile * 16 + node) * 96 + c4];
    sl[node][c4 * 4] = v.x; sl[node][c4 * 4 + 1] = v.y;
    sl[node][c4 * 4 + 2] = v.z; sl[node][c4 * 4 + 3] = v.w;
  }
  __syncthreads();
  u32* op = seqp + (size_t)tile * 3072;
  for (int o = tid; o < 3072; o += 128) {
    int m = o & 15, p = (o >> 4) & 7, t = o >> 7;
    op[o] = cvtpk(sl[m][t * 16 + 2 * p], sl[m][t * 16 + 2 * p + 1]);
  }
}

// ============ K1: MFMA GRU, per-mt accumulator schedule (low reg pressure) ============
__global__ __launch_bounds__(256, 4) void k_gru(
    const u32* __restrict__ seqp, const float* __restrict__ w_ih,
    const float* __restrict__ w_hh, const float* __restrict__ b_ih,
    const float* __restrict__ b_hh, u32* __restrict__ htile,
    float* __restrict__ h_last) {
  __shared__ u32 frg[36 * 256];  // 36KB: 0..11 = gi (w_ih+bias slot), 12+mt*2+kt = w_hh
  int tid = threadIdx.x;
  for (int i = tid; i < 9216; i += 256) {
    int v = i & 3, lane = (i >> 2) & 63, f = i >> 8;
    int g = lane >> 4, mm = lane & 15;
    u32 val = 0u;
    if (f < 12) {
      int gate = f * 16 + mm;
      if (g < 2) {
        int dim = g * 8 + 2 * v;
        val = pack_bf(w_ih[gate * 16 + dim], w_ih[gate * 16 + dim + 1]);
      } else if (g == 2 && v == 0) {
        float bias = b_ih[gate] + (gate < 128 ? b_hh[gate] : 0.f);
        val = pack_bf(bias, 0.f);
      }
    } else {
      int ff = f - 12, mt = ff >> 1, kt = ff & 1;
      int gate = mt * 16 + mm;
      int ch0 = CH0(kt, g, v);
      val = pack_bf(w_hh[gate * 64 + ch0], w_hh[gate * 64 + ch0 + 1]);
    }
    frg[i] = val;
  }
  __syncthreads();
  int w = tid >> 6, lane = tid & 63, g = lane >> 4, m = lane & 15;
  int tile = blockIdx.x * 4 + w;
  if (tile >= NTILE) return;
  int n = tile * 16 + m;
  const f32x4 Z = {0.f, 0.f, 0.f, 0.f};
  float bhn[4][4];
#pragma unroll
  for (int mt = 0; mt < 4; ++mt)
#pragma unroll
    for (int r = 0; r < 4; ++r) bhn[mt][r] = b_hh[128 + mt * 16 + g * 4 + r];
  f32x4 Hc[4] = {Z, Z, Z, Z};
  u32 hb0[4] = {0u, 0u, 0u, 0u}, hb1[4] = {0u, 0u, 0u, 0u};
  const u32* sp = seqp + (size_t)tile * 3072;
  u32* hp = htile + (size_t)tile * 24 * 512;

  for (int t = 0; t < 24; ++t) {
    u32 sf0, sf1, sf2, sf3;
    if (g < 2) {
      sf0 = sp[(t * 8 + g * 4 + 0) * 16 + m];
      sf1 = sp[(t * 8 + g * 4 + 1) * 16 + m];
      sf2 = sp[(t * 8 + g * 4 + 2) * 16 + m];
      sf3 = sp[(t * 8 + g * 4 + 3) * 16 + m];
    } else if (g == 2) { sf0 = 0x00003f80u; sf1 = sf2 = sf3 = 0u; }
    else { sf0 = sf1 = sf2 = sf3 = 0u; }
    short8 sB  = mk4(sf0, sf1, sf2, sf3);
    short8 hB0 = mk4(hb0[0], hb0[1], hb0[2], hb0[3]);
    short8 hB1 = mk4(hb1[0], hb1[1], hb1[2], hb1[3]);
    // per output tile: compute r,z,n,ghn then consume — only 4 C-frags live
#pragma unroll
    for (int mt = 0; mt < 4; ++mt) {
      f32x4 Cr = mfma16(ldfrag(&frg[(mt * 64 + lane) * 4]), sB, Z);
      f32x4 Cz = mfma16(ldfrag(&frg[((4 + mt) * 64 + lane) * 4]), sB, Z);
      f32x4 Cn = mfma16(ldfrag(&frg[((8 + mt) * 64 + lane) * 4]), sB, Z);
      f32x4 Cghn = mfma16(ldfrag(&frg[((12 + (8 + mt) * 2) * 64 + lane) * 4]), hB0, Z);
      Cr = mfma16(ldfrag(&frg[((12 + mt * 2) * 64 + lane) * 4]), hB0, Cr);
      Cz = mfma16(ldfrag(&frg[((12 + (4 + mt) * 2) * 64 + lane) * 4]), hB0, Cz);
      Cghn = mfma16(ldfrag(&frg[((12 + (8 + mt) * 2 + 1) * 64 + lane) * 4]), hB1, Cghn);
      Cr = mfma16(ldfrag(&frg[((12 + mt * 2 + 1) * 64 + lane) * 4]), hB1, Cr);
      Cz = mfma16(ldfrag(&frg[((12 + (4 + mt) * 2 + 1) * 64 + lane) * 4]), hB1, Cz);
#pragma unroll
      for (int r = 0; r < 4; ++r) {
        float rr = sigm(Cr[r]);
        float zz = sigm(Cz[r]);
        float nn = tanh_f(Cn[r] + rr * (Cghn[r] + bhn[mt][r]));
        Hc[mt][r] = nn + zz * (Hc[mt][r] - nn);
      }
    }
    hb0[0] = cvtpk(Hc[0][0], Hc[0][1]); hb0[1] = cvtpk(Hc[0][2], Hc[0][3]);
    hb0[2] = cvtpk(Hc[1][0], Hc[1][1]); hb0[3] = cvtpk(Hc[1][2], Hc[1][3]);
    hb1[0] = cvtpk(Hc[2][0], Hc[2][1]); hb1[1] = cvtpk(Hc[2][2], Hc[2][3]);
    hb1[2] = cvtpk(Hc[3][0], Hc[3][1]); hb1[3] = cvtpk(Hc[3][2], Hc[3][3]);
    u32* op = hp + t * 512;
    *(uint2*)&op[(0 * 4 + g) * 32 + 2 * m] = make_uint2(hb0[0], hb0[1]);
    *(uint2*)&op[(1 * 4 + g) * 32 + 2 * m] = make_uint2(hb0[2], hb0[3]);
    *(uint2*)&op[(2 * 4 + g) * 32 + 2 * m] = make_uint2(hb1[0], hb1[1]);
    *(uint2*)&op[(3 * 4 + g) * 32 + 2 * m] = make_uint2(hb1[2], hb1[3]);
  }
#pragma unroll
  for (int mt = 0; mt < 4; ++mt)
    *(f32x4*)&h_last[(size_t)n * 64 + mt * 16 + g * 4] = Hc[mt];
}

// ============ K2: fold Wq/Wk/bq + scale into M (64x256) and abk (256) ============
__global__ void k_prep(const float* __restrict__ aw, const float* __restrict__ ab,
                       float* __restrict__ Mall, float* __restrict__ abk) {
  int j = threadIdx.x;
  int h = j >> 6, cp = j & 63;
  if (blockIdx.x < 64) {
    int c = blockIdx.x;
    float acc = 0.f;
    for (int d = 0; d < 16; ++d)
      acc += aw[(h * 16 + d) * 64 + c] * aw[(64 + h * 16 + d) * 64 + cp];
    Mall[c * 256 + j] = 0.25f * acc;
  } else {
    float acc = 0.f;
    for (int d = 0; d < 16; ++d)
      acc += ab[h * 16 + d] * aw[(64 + h * 16 + d) * 64 + cp];
    abk[j] = 0.25f * acc;
  }
}

// ============ K3: fused attention: U-MFMA + online scores/PV + V/out/proj MFMAs ============
__global__ __launch_bounds__(256, 2) void k_attn2(
    const u32* __restrict__ htile, const float* __restrict__ Mall,
    const float* __restrict__ abk, const float* __restrict__ aw,
    const float* __restrict__ ab, const float* __restrict__ out_w,
    const float* __restrict__ out_b, const float* __restrict__ proj_w,
    const float* __restrict__ proj_b, const float* __restrict__ h_last,
    const float* __restrict__ x, u32* __restrict__ xin_b) {
  __shared__ u32 mfrg[32 * 256];  // 32KB Mall frags
  __shared__ u32 vfrg[8 * 256];   // Wv
  __shared__ u32 ofrg[8 * 256];   // out_w
  __shared__ u32 pfrg[8 * 256];   // proj_w
  __shared__ float abks[256];
  __shared__ float smallb[192];   // out_b | proj_b | bv
  int tid = threadIdx.x;
  for (int i = tid; i < 32 * 256; i += 256) {
    int v = i & 3, lane = (i >> 2) & 63, f = i >> 8;
    int kt = f & 1, mt = f >> 1;
    int g = lane >> 4, mm = lane & 15;
    int jj = mt * 16 + mm, ch0 = CH0(kt, g, v);
    mfrg[i] = pack_bf(Mall[ch0 * 256 + jj], Mall[(ch0 + 1) * 256 + jj]);
  }
  for (int i = tid; i < 8 * 256; i += 256) {
    int v = i & 3, lane = (i >> 2) & 63, f = i >> 8;
    int kt = f & 1, mt = f >> 1;
    int g = lane >> 4, mm = lane & 15;
    int vo = mt * 16 + mm, ch0 = CH0(kt, g, v);
    vfrg[i] = pack_bf(aw[(128 + vo) * 64 + ch0], aw[(128 + vo) * 64 + ch0 + 1]);
    ofrg[i] = pack_bf(out_w[vo * 64 + ch0], out_w[vo * 64 + ch0 + 1]);
    pfrg[i] = pack_bf(proj_w[vo * 64 + ch0], proj_w[vo * 64 + ch0 + 1]);
  }
  if (tid < 256) abks[tid] = abk[tid];
  if (tid < 64) {
    smallb[tid] = out_b[tid];
    smallb[64 + tid] = proj_b[tid];
    smallb[128 + tid] = ab[128 + tid];
  }
  __syncthreads();
  int w = tid >> 6, lane = tid & 63, g = lane >> 4, m = lane & 15;
  int tile = blockIdx.x * 4 + w;
  if (tile >= NTILE) return;
  int n = tile * 16 + m;
  const f32x4 Z = {0.f, 0.f, 0.f, 0.f};
  const u32* hp = htile + (size_t)tile * 24 * 512;
  // h23 frags
  u32 h23d[2][4];
#pragma unroll
  for (int kt = 0; kt < 2; ++kt)
#pragma unroll
    for (int jh = 0; jh < 2; ++jh) {
      uint2 v = *(const uint2*)&hp[23 * 512 + ((kt * 2 + jh) * 4 + g) * 32 + 2 * m];
      h23d[kt][jh * 2] = v.x; h23d[kt][jh * 2 + 1] = v.y;
    }
  // U = Mall^T h23 + abk (C-layout: Uc[mt][r] = U[node m][mt*16+g*4+r])
  f32x4 Uc[16];
#pragma unroll
  for (int mt = 0; mt < 16; ++mt) Uc[mt] = *(const f32x4*)&abks[mt * 16 + g * 4];
#pragma unroll
  for (int mt = 0; mt < 16; ++mt)
#pragma unroll
    for (int kt = 0; kt < 2; ++kt)
      Uc[mt] = mfma16(ldfrag(&mfrg[((mt * 2 + kt) * 64 + lane) * 4]),
                      mk4(h23d[kt][0], h23d[kt][1], h23d[kt][2], h23d[kt][3]), Uc[mt]);
  // single pass over t: scores + exp + hbar (no-max softmax: |s| small, bounded)
  float den[4] = {0.f, 0.f, 0.f, 0.f};
  float hbar[4][4][4] = {};
  for (int t = 0; t < 24; ++t) {
    u32 hd[2][4];
#pragma unroll
    for (int kt = 0; kt < 2; ++kt)
#pragma unroll
      for (int jh = 0; jh < 2; ++jh) {
        uint2 v = *(const uint2*)&hp[t * 512 + ((kt * 2 + jh) * 4 + g) * 32 + 2 * m];
        hd[kt][jh * 2] = v.x; hd[kt][jh * 2 + 1] = v.y;
      }
    float hF[4][4];
#pragma unroll
    for (int kt = 0; kt < 2; ++kt)
#pragma unroll
      for (int jh = 0; jh < 2; ++jh)
#pragma unroll
        for (int jl = 0; jl < 2; ++jl) {
          u32 d = hd[kt][jh * 2 + jl];
          hF[kt * 2 + jh][jl * 2] = lo_f(d);
          hF[kt * 2 + jh][jl * 2 + 1] = hi_f(d);
        }
    float s[4];
#pragma unroll
    for (int h = 0; h < 4; ++h) {
      float acc = 0.f;
#pragma unroll
      for (int mt2 = 0; mt2 < 4; ++mt2)
#pragma unroll
        for (int r = 0; r < 4; ++r) acc += Uc[h * 4 + mt2][r] * hF[mt2][r];
      acc += __shfl_xor(acc, 16);
      acc += __shfl_xor(acc, 32);
      s[h] = acc;
    }
#pragma unroll
    for (int h = 0; h < 4; ++h) {
      float p = __expf(s[h]);
      den[h] += p;
#pragma unroll
      for (int mt2 = 0; mt2 < 4; ++mt2)
#pragma unroll
        for (int r = 0; r < 4; ++r) hbar[h][mt2][r] += p * hF[mt2][r];
    }
  }
  // o = Wv hbar / den + bv (per head)
  float oc[4][4];
#pragma unroll
  for (int h = 0; h < 4; ++h) {
    f32x4 C = Z;
#pragma unroll
    for (int kt = 0; kt < 2; ++kt) {
      short8 B = mk4(cvtpk(hbar[h][kt * 2][0], hbar[h][kt * 2][1]),
                     cvtpk(hbar[h][kt * 2][2], hbar[h][kt * 2][3]),
                     cvtpk(hbar[h][kt * 2 + 1][0], hbar[h][kt * 2 + 1][1]),
                     cvtpk(hbar[h][kt * 2 + 1][2], hbar[h][kt * 2 + 1][3]));
      C = mfma16(ldfrag(&vfrg[((h * 2 + kt) * 64 + lane) * 4]), B, C);
    }
    float inv = 1.f / den[h];
    f32x4 bv = *(const f32x4*)&smallb[128 + h * 16 + g * 4];
#pragma unroll
    for (int r = 0; r < 4; ++r) oc[h][r] = C[r] * inv + bv[r];
  }
  // al = out_w o + out_b
  f32x4 alc[4];
#pragma unroll
  for (int mt = 0; mt < 4; ++mt) alc[mt] = *(const f32x4*)&smallb[mt * 16 + g * 4];
#pragma unroll
  for (int kt = 0; kt < 2; ++kt) {
    short8 B = mk4(cvtpk(oc[kt * 2][0], oc[kt * 2][1]),
                   cvtpk(oc[kt * 2][2], oc[kt * 2][3]),
                   cvtpk(oc[kt * 2 + 1][0], oc[kt * 2 + 1][1]),
                   cvtpk(oc[kt * 2 + 1][2], oc[kt * 2 + 1][3]));
#pragma unroll
    for (int mt = 0; mt < 4; ++mt)
      alc[mt] = mfma16(ldfrag(&ofrg[((mt * 2 + kt) * 64 + lane) * 4]), B, alc[mt]);
  }
  // last = h23(fp32) + al ; te = proj_w last + proj_b
  float lc[4][4];
#pragma unroll
  for (int mt = 0; mt < 4; ++mt) {
    f32x4 hl = *(const f32x4*)&h_last[(size_t)n * 64 + mt * 16 + g * 4];
#pragma unroll
    for (int r = 0; r < 4; ++r) lc[mt][r] = hl[r] + alc[mt][r];
  }
  f32x4 tec[4];
#pragma unroll
  for (int mt = 0; mt < 4; ++mt) tec[mt] = *(const f32x4*)&smallb[64 + mt * 16 + g * 4];
#pragma unroll
  for (int kt = 0; kt < 2; ++kt) {
    short8 B = mk4(cvtpk(lc[kt * 2][0], lc[kt * 2][1]),
                   cvtpk(lc[kt * 2][2], lc[kt * 2][3]),
                   cvtpk(lc[kt * 2 + 1][0], lc[kt * 2 + 1][1]),
                   cvtpk(lc[kt * 2 + 1][2], lc[kt * 2 + 1][3]));
#pragma unroll
    for (int mt = 0; mt < 4; ++mt)
      tec[mt] = mfma16(ldfrag(&pfrg[((mt * 2 + kt) * 64 + lane) * 4]), B, tec[mt]);
  }
  // te -> xin_b dw 32..63: per-lane uint2 scatter (8B-aligned, no LDS transpose)
#pragma unroll
  for (int mt = 0; mt < 4; ++mt)
    *(uint2*)&xin_b[(size_t)n * 64 + 32 + mt * 8 + g * 2] =
        make_uint2(cvtpk(tec[mt][0], tec[mt][1]), cvtpk(tec[mt][2], tec[mt][3]));
  // x -> xin_b dw 0..31: direct coalesced conversion (lane (i2,q) owns node i2, block q)
  {
    int i2 = lane >> 2, q = lane & 3;
    int n2 = tile * 16 + i2;
#pragma unroll
    for (int j = 0; j < 2; ++j) {
      float4 x0 = ((const float4*)x)[(size_t)n2 * 16 + q * 4 + 2 * j];
      float4 x1 = ((const float4*)x)[(size_t)n2 * 16 + q * 4 + 2 * j + 1];
      uint4 vv;
      vv.x = cvtpk(x0.x, x0.y); vv.y = cvtpk(x0.z, x0.w);
      vv.z = cvtpk(x1.x, x1.y); vv.w = cvtpk(x1.z, x1.w);
      *(uint4*)&xin_b[(size_t)n2 * 64 + q * 8 + j * 4] = vv;
    }
  }
}

// ============ CSR construction ============
__global__ void k_zero(int* __restrict__ p, int n) {
  int i = blockIdx.x * 256 + threadIdx.x;
  if (i < n) p[i] = 0;
}
__global__ void k_count(const int* __restrict__ ei, int* __restrict__ rowptr) {
  int e = blockIdx.x * 256 + threadIdx.x;
  if (e >= ETOT) return;
  int d = (e < NEDGE) ? ei[NEDGE + e] : (e - NEDGE);
  atomicAdd(&rowptr[d + 1], 1);
}
__global__ void k_scan1(int* __restrict__ data, int* __restrict__ bsum, int n) {
  __shared__ int s[256];
  int i = blockIdx.x * 256 + threadIdx.x;
  s[threadIdx.x] = (i < n) ? data[i] : 0;
  __syncthreads();
  for (int off = 1; off < 256; off <<= 1) {
    int t = (threadIdx.x >= off) ? s[threadIdx.x - off] : 0;
    __syncthreads();
    s[threadIdx.x] += t;
    __syncthreads();
  }
  if (i < n) data[i] = s[threadIdx.x];
  if (threadIdx.x == 255) bsum[blockIdx.x] = s[255];
}
__global__ void k_scan2(int* __restrict__ bsum, int n) {
  __shared__ int s[256];
  int t = threadIdx.x;
  s[t] = (t < n) ? bsum[t] : 0;
  __syncthreads();
  for (int off = 1; off < 256; off <<= 1) {
    int v = (t >= off) ? s[t - off] : 0;
    __syncthreads();
    s[t] += v;
    __syncthreads();
  }
  if (t < n) bsum[t] = s[t];
}
__global__ void k_scan3(int* __restrict__ data, const int* __restrict__ bsum, int n) {
  int i = blockIdx.x * 256 + threadIdx.x;
  if (blockIdx.x > 0 && i < n) data[i] += bsum[blockIdx.x - 1];
}
__global__ void k_copycur(const int* __restrict__ rowptr, int* __restrict__ wcur, int n) {
  int i = blockIdx.x * 256 + threadIdx.x;
  if (i < n) wcur[i] = rowptr[i];
}
__global__ void k_scatter(const int* __restrict__ ei, int* __restrict__ wcur,
                          int* __restrict__ csr_src) {
  int e = blockIdx.x * 256 + threadIdx.x;
  if (e >= ETOT) return;
  int s = (e < NEDGE) ? ei[e] : (e - NEDGE);
  int d = (e < NEDGE) ? ei[NEDGE + e] : (e - NEDGE);
  int pos = atomicAdd(&wcur[d], 1);
  csr_src[pos] = s;
}

// ============ GAT transform (bf16 in/out) + fused attention logits ============
template <int KT>
__global__ __launch_bounds__(256, 2) void k_gat_gemm(
    const u32* __restrict__ A, const float* __restrict__ W,
    const float* __restrict__ at_s, const float* __restrict__ at_d,
    u32* __restrict__ Cout, float* __restrict__ as_out, float* __restrict__ ad_out) {
  __shared__ u32 frg[8 * KT * 256];
  int tid = threadIdx.x;
  int mt0 = blockIdx.y * 8;
  for (int i = tid; i < 8 * KT * 256; i += 256) {
    int v = i & 3, lane = (i >> 2) & 63, f = i >> 8;
    int kt = f % KT, mt = f / KT;
    int g = lane >> 4, mm = lane & 15;
    int o = (mt0 + mt) * 16 + mm;
    int ch0 = CH0(kt, g, v);
    frg[i] = pack_bf(W[ch0 * 256 + o], W[(ch0 + 1) * 256 + o]);
  }
  __syncthreads();
  int w = tid >> 6, lane = tid & 63, g = lane >> 4, m = lane & 15;
  int n0 = blockIdx.x * 128 + w * 32;
  const f32x4 Z = {0.f, 0.f, 0.f, 0.f};
  u32 bfr[2][KT][4];
#pragma unroll
  for (int nt = 0; nt < 2; ++nt) {
    int nn = n0 + nt * 16 + m;
    int nc = nn < N_NODES ? nn : N_NODES - 1;
#pragma unroll
    for (int kt = 0; kt < KT; ++kt)
#pragma unroll
      for (int jh = 0; jh < 2; ++jh) {
        uint2 uv = *(const uint2*)&A[(size_t)nc * (KT * 16) + (kt * 2 + jh) * 8 + g * 2];
        bfr[nt][kt][jh * 2] = uv.x; bfr[nt][kt][jh * 2 + 1] = uv.y;
      }
  }
  float ps[2][2] = {{0.f, 0.f}, {0.f, 0.f}};
  float pd[2][2] = {{0.f, 0.f}, {0.f, 0.f}};
#pragma unroll
  for (int mt = 0; mt < 8; ++mt) {
    f32x4 C[2] = {Z, Z};
#pragma unroll
    for (int kt = 0; kt < KT; ++kt) {
      short8 a = ldfrag(&frg[((mt * KT + kt) * 64 + lane) * 4]);
#pragma unroll
      for (int nt = 0; nt < 2; ++nt)
        C[nt] = mfma16(a, mk4(bfr[nt][kt][0], bfr[nt][kt][1], bfr[nt][kt][2], bfr[nt][kt][3]), C[nt]);
    }
    int j0 = (mt0 + mt) * 16 + g * 4;
    f32x4 as4 = *(const f32x4*)&at_s[j0];
    f32x4 ad4 = *(const f32x4*)&at_d[j0];
#pragma unroll
    for (int nt = 0; nt < 2; ++nt) {
      int nn = n0 + nt * 16 + m;
#pragma unroll
      for (int r = 0; r < 4; ++r) {
        ps[nt][mt >> 2] += C[nt][r] * as4[r];
        pd[nt][mt >> 2] += C[nt][r] * ad4[r];
      }
      if (nn < N_NODES)
        *(uint2*)&Cout[(size_t)nn * 128 + (mt0 + mt) * 8 + g * 2] =
            make_uint2(cvtpk(C[nt][0], C[nt][1]), cvtpk(C[nt][2], C[nt][3]));
    }
  }
#pragma unroll
  for (int nt = 0; nt < 2; ++nt)
#pragma unroll
    for (int hh = 0; hh < 2; ++hh) {
      float s = ps[nt][hh];
      s += __shfl_xor(s, 16); s += __shfl_xor(s, 32);
      float d = pd[nt][hh];
      d += __shfl_xor(d, 16); d += __shfl_xor(d, 32);
      int nn = n0 + nt * 16 + m;
      if (g == 0 && nn < N_NODES) {
        int h = blockIdx.y * 2 + hh;
        as_out[nn * 4 + h] = s;
        ad_out[nn * 4 + h] = d;
      }
    }
}

// ============ GAT1 aggregation: bf16 gather, bf16 out ============
__global__ __launch_bounds__(256) void k_gat_agg1(
    const u32* __restrict__ htb, const float* __restrict__ as_,
    const float* __restrict__ ad_, const int* __restrict__ rowptr,
    const int* __restrict__ csr_src, const float* __restrict__ bias,
    u32* __restrict__ h1b) {
  int w = threadIdx.x >> 6, lane = threadIdx.x & 63;
  int n = blockIdx.x * 4 + w;
  int hg = lane >> 4;
  float adh = ad_[n * 4 + hg];
  int beg = rowptr[n], end = rowptr[n + 1];
  float den = 0.f;
  float4 acc = {0.f, 0.f, 0.f, 0.f};
  for (int e = beg; e < end; ++e) {
    int s = csr_src[e];
    float ev = as_[s * 4 + hg] + adh;
    ev = ev > 0.f ? ev : 0.2f * ev;
    float p = __expf(ev);
    den += p;
    uint2 hv = ((const uint2*)htb)[(size_t)s * 64 + lane];
    acc.x += p * lo_f(hv.x); acc.y += p * hi_f(hv.x);
    acc.z += p * lo_f(hv.y); acc.w += p * hi_f(hv.y);
  }
  float inv = 1.f / den;
  float4 b4 = *(const float4*)&bias[lane * 4];
  float o0 = elu_f(acc.x * inv + b4.x);
  float o1 = elu_f(acc.y * inv + b4.y);
  float o2 = elu_f(acc.z * inv + b4.z);
  float o3 = elu_f(acc.w * inv + b4.w);
  ((uint2*)h1b)[(size_t)n * 64 + lane] = make_uint2(cvtpk(o0, o1), cvtpk(o2, o3));
}

// ============ GAT2 aggregation: bf16 gather, head-mean + elu + fused final linear ============
__global__ __launch_bounds__(256) void k_gat_agg2(
    const u32* __restrict__ htb, const float* __restrict__ as_,
    const float* __restrict__ ad_, const int* __restrict__ rowptr,
    const int* __restrict__ csr_src, const float* __restrict__ bias,
    const float* __restrict__ lin_w, const float* __restrict__ lin_b,
    float* __restrict__ out) {
  int w = threadIdx.x >> 6, lane = threadIdx.x & 63;
  int n = blockIdx.x * 4 + w;
  int hg = lane >> 4, q = lane & 15;
  float adh = ad_[n * 4 + hg];
  int beg = rowptr[n], end = rowptr[n + 1];
  float den = 0.f;
  float4 acc = {0.f, 0.f, 0.f, 0.f};
  for (int e = beg; e < end; ++e) {
    int s = csr_src[e];
    float ev = as_[s * 4 + hg] + adh;
    ev = ev > 0.f ? ev : 0.2f * ev;
    float p = __expf(ev);
    den += p;
    uint2 hv = ((const uint2*)htb)[(size_t)s * 64 + lane];
    acc.x += p * lo_f(hv.x); acc.y += p * hi_f(hv.x);
    acc.z += p * lo_f(hv.y); acc.w += p * hi_f(hv.y);
  }
  float inv = 1.f / den;
  float v0 = acc.x * inv, v1 = acc.y * inv, v2 = acc.z * inv, v3 = acc.w * inv;
  v0 += __shfl_xor(v0, 16); v0 += __shfl_xor(v0, 32);
  v1 += __shfl_xor(v1, 16); v1 += __shfl_xor(v1, 32);
  v2 += __shfl_xor(v2, 16); v2 += __shfl_xor(v2, 32);
  v3 += __shfl_xor(v3, 16); v3 += __shfl_xor(v3, 32);
  float4 b4 = *(const float4*)&bias[q * 4];
  float o0 = elu_f(v0 * 0.25f + b4.x);
  float o1 = elu_f(v1 * 0.25f + b4.y);
  float o2 = elu_f(v2 * 0.25f + b4.z);
  float o3 = elu_f(v3 * 0.25f + b4.w);
  float4 lw = *(const float4*)&lin_w[q * 4];
  float p2 = o0 * lw.x + o1 * lw.y + o2 * lw.z + o3 * lw.w;
  p2 += __shfl_xor(p2, 1); p2 += __shfl_xor(p2, 2);
  p2 += __shfl_xor(p2, 4); p2 += __shfl_xor(p2, 8);
  if (lane == 0) out[n] = p2 + lin_b[0];
}

extern "C" void kernel_launch(void* const* d_in, const int* in_sizes, int n_in,
                              void* d_out, int out_size, void* d_ws, size_t ws_size,
                              hipStream_t stream) {
  const float* x         = (const float*)d_in[0];
  const int*   ei        = (const int*)d_in[1];
  const float* seq       = (const float*)d_in[2];
  const float* gru_w_ih  = (const float*)d_in[3];
  const float* gru_w_hh  = (const float*)d_in[4];
  const float* gru_b_ih  = (const float*)d_in[5];
  const float* gru_b_hh  = (const float*)d_in[6];
  const float* attn_in_w = (const float*)d_in[7];
  const float* attn_in_b = (const float*)d_in[8];
  const float* attn_out_w= (const float*)d_in[9];
  const float* attn_out_b= (const float*)d_in[10];
  const float* proj_w    = (const float*)d_in[11];
  const float* proj_b    = (const float*)d_in[12];
  const float* gat1_w    = (const float*)d_in[13];
  const float* g1as      = (const float*)d_in[14];
  const float* g1ad      = (const float*)d_in[15];
  const float* gat1_b    = (const float*)d_in[16];
  const float* gat2_w    = (const float*)d_in[17];
  const float* g2as      = (const float*)d_in[18];
  const float* g2ad      = (const float*)d_in[19];
  const float* gat2_b    = (const float*)d_in[20];
  const float* lin_w     = (const float*)d_in[21];
  const float* lin_b     = (const float*)d_in[22];
  float* out = (float*)d_out;

  char* p = (char*)d_ws;
  auto alloc = [&](size_t bytes) {
    char* r = p;
    p += (bytes + 255) & ~(size_t)255;
    return r;
  };
  char*  region0 = alloc((size_t)NTILE * 24 * 512 * 4);     // 153.6MB: htile -> htb/h1b
  u32*   seqp    = (u32*)  alloc((size_t)NTILE * 3072 * 4); // 38.4MB
  float* h_last  = (float*)alloc((size_t)N_NODES * 64 * 4); // 12.8MB
  u32*   xin_b   = (u32*)  alloc((size_t)N_NODES * 64 * 4); // 12.8MB
  float* Mall    = (float*)alloc(64 * 256 * 4);
  float* abk     = (float*)alloc(256 * 4);
  float* a1s     = (float*)alloc((size_t)N_NODES * 4 * 4);
  float* a1d     = (float*)alloc((size_t)N_NODES * 4 * 4);
  float* a2s     = (float*)alloc((size_t)N_NODES * 4 * 4);
  float* a2d     = (float*)alloc((size_t)N_NODES * 4 * 4);
  int*   rowptr  = (int*)  alloc((size_t)(N_NODES + 1) * 4);
  int*   wcur    = (int*)  alloc((size_t)N_NODES * 4);
  int*   csr     = (int*)  alloc((size_t)ETOT * 4);
  int*   bsum    = (int*)  alloc(256 * 4);
  u32* htile = (u32*)region0;
  u32* htb   = (u32*)region0;                          // 25.6MB, after htile dead
  u32* h1b   = (u32*)(region0 + ((size_t)32 << 20));   // 25.6MB at +32MB

  // temporal encoder
  k_seqpack<<<NTILE, 128, 0, stream>>>(seq, seqp);
  k_gru<<<(NTILE + 3) / 4, 256, 0, stream>>>(seqp, gru_w_ih, gru_w_hh, gru_b_ih,
                                             gru_b_hh, htile, h_last);
  k_prep<<<65, 256, 0, stream>>>(attn_in_w, attn_in_b, Mall, abk);
  k_attn2<<<(NTILE + 3) / 4, 256, 0, stream>>>(htile, Mall, abk, attn_in_w, attn_in_b,
                                               attn_out_w, attn_out_b, proj_w, proj_b,
                                               h_last, x, xin_b);
  // CSR (dst-sorted), shared by both GAT layers
  k_zero<<<196, 256, 0, stream>>>(rowptr, N_NODES + 1);
  k_count<<<(ETOT + 255) / 256, 256, 0, stream>>>(ei, rowptr);
  k_scan1<<<196, 256, 0, stream>>>(rowptr, bsum, N_NODES + 1);
  k_scan2<<<1, 256, 0, stream>>>(bsum, 196);
  k_scan3<<<196, 256, 0, stream>>>(rowptr, bsum, N_NODES + 1);
  k_copycur<<<(N_NODES + 255) / 256, 256, 0, stream>>>(rowptr, wcur, N_NODES);
  k_scatter<<<(ETOT + 255) / 256, 256, 0, stream>>>(ei, wcur, csr);
  // GAT1 (concat + elu)
  k_gat_gemm<4><<<dim3(391, 2), 256, 0, stream>>>(xin_b, gat1_w, g1as, g1ad,
                                                  htb, a1s, a1d);
  k_gat_agg1<<<12500, 256, 0, stream>>>(htb, a1s, a1d, rowptr, csr, gat1_b, h1b);
  // GAT2 (mean + elu + final linear)
  k_gat_gemm<8><<<dim3(391, 2), 256, 0, stream>>>(h1b, gat2_w, g2as, g2ad,
                                                  htb, a2s, a2d);
  k_gat_agg2<<<12500, 256, 0, stream>>>(htb, a2s, a2d, rowptr, csr, gat2_b,
                                        lin_w, lin_b, out);
}

// Round 9
// 789.243 us; speedup vs baseline: 1.2924x; 1.2679x over previous
//
#include <hip/hip_runtime.h>
#include <hip/hip_bf16.h>

#define N_NODES 50000
#define NTILE   3125     // N_NODES/16 exactly
#define NEDGE   800000
#define ETOT    850000

typedef unsigned int u32;
typedef unsigned short u16;
typedef __attribute__((ext_vector_type(8))) short short8;
typedef __attribute__((ext_vector_type(4))) float f32x4;

union FragU { u32 u[4]; short8 s; };

static __device__ __forceinline__ u16 f2b(float f) {
  union { float f; u32 u; } x; x.f = f;
  u32 r = x.u + 0x7fffu + ((x.u >> 16) & 1u);
  return (u16)(r >> 16);
}
static __device__ __forceinline__ u32 pack_bf(float a, float b) {
  return (u32)f2b(a) | ((u32)f2b(b) << 16);
}
static __device__ __forceinline__ u32 cvtpk(float lo, float hi) {
  u32 r; asm("v_cvt_pk_bf16_f32 %0, %1, %2" : "=v"(r) : "v"(lo), "v"(hi));
  return r;
}
static __device__ __forceinline__ float lo_f(u32 p) {
  union { u32 u; float f; } x; x.u = p << 16; return x.f;
}
static __device__ __forceinline__ float hi_f(u32 p) {
  union { u32 u; float f; } x; x.u = p & 0xffff0000u; return x.f;
}
static __device__ __forceinline__ short8 mk4(u32 a, u32 b, u32 c, u32 d) {
  FragU f; f.u[0] = a; f.u[1] = b; f.u[2] = c; f.u[3] = d; return f.s;
}
static __device__ __forceinline__ short8 ldfrag(const u32* p) {
  uint4 v = *(const uint4*)p;
  FragU f; f.u[0] = v.x; f.u[1] = v.y; f.u[2] = v.z; f.u[3] = v.w; return f.s;
}
static __device__ __forceinline__ f32x4 mfma16(short8 a, short8 b, f32x4 c) {
  return __builtin_amdgcn_mfma_f32_16x16x32_bf16(a, b, c, 0, 0, 0);
}
static __device__ __forceinline__ float sigm(float x) { return 1.f / (1.f + __expf(-x)); }
static __device__ __forceinline__ float tanh_f(float x) { return 1.f - 2.f / (__expf(2.f * x) + 1.f); }
static __device__ __forceinline__ float elu_f(float x) { return x > 0.f ? x : __expf(x) - 1.f; }

// shared A/B k-slot bijection: slot(kt, g, j) -> channel pair base
#define CH0(kt, g, j) (((kt) * 2 + ((j) >> 1)) * 16 + (g) * 4 + ((j) & 1) * 2)

// ============ K0: pack seq fp32 -> bf16 tile layout [tile][t][p=dimpair][m] ============
__global__ __launch_bounds__(128) void k_seqpack(const float* __restrict__ seq,
                                                 u32* __restrict__ seqp) {
  __shared__ float sl[16][385];
  int tile = blockIdx.x, tid = threadIdx.x;
  const float4* s4 = (const float4*)seq;
  for (int i = tid; i < 1536; i += 128) {
    int node = i / 96, c4 = i - node * 96;
    float4 v = s4[(size_t)(tile * 16 + node) * 96 + c4];
    sl[node][c4 * 4] = v.x; sl[node][c4 * 4 + 1] = v.y;
    sl[node][c4 * 4 + 2] = v.z; sl[node][c4 * 4 + 3] = v.w;
  }
  __syncthreads();
  u32* op = seqp + (size_t)tile * 3072;
  for (int o = tid; o < 3072; o += 128) {
    int m = o & 15, p = (o >> 4) & 7, t = o >> 7;
    op[o] = cvtpk(sl[m][t * 16 + 2 * p], sl[m][t * 16 + 2 * p + 1]);
  }
}

// ============ K1: MFMA GRU, per-mt schedule + LICM-defeating frag offset ============
// Round-9 fix: all 36 frag LDS addresses were loop-invariant -> LICM hoisted
// 576B/lane of LDS loads out of the t-loop -> spill -> ~1GB scratch traffic.
// `fo` is laundered opaque每 iteration so frags are re-read from LDS each step.
__global__ __launch_bounds__(256, 4) void k_gru(
    const u32* __restrict__ seqp, const float* __restrict__ w_ih,
    const float* __restrict__ w_hh, const float* __restrict__ b_ih,
    const float* __restrict__ b_hh, u32* __restrict__ htile,
    float* __restrict__ h_last) {
  __shared__ u32 frg[36 * 256];  // 36KB: 0..11 = gi (w_ih+bias slot), 12+mt*2+kt = w_hh
  int tid = threadIdx.x;
  for (int i = tid; i < 9216; i += 256) {
    int v = i & 3, lane = (i >> 2) & 63, f = i >> 8;
    int g = lane >> 4, mm = lane & 15;
    u32 val = 0u;
    if (f < 12) {
      int gate = f * 16 + mm;
      if (g < 2) {
        int dim = g * 8 + 2 * v;
        val = pack_bf(w_ih[gate * 16 + dim], w_ih[gate * 16 + dim + 1]);
      } else if (g == 2 && v == 0) {
        float bias = b_ih[gate] + (gate < 128 ? b_hh[gate] : 0.f);
        val = pack_bf(bias, 0.f);
      }
    } else {
      int ff = f - 12, mt = ff >> 1, kt = ff & 1;
      int gate = mt * 16 + mm;
      int ch0 = CH0(kt, g, v);
      val = pack_bf(w_hh[gate * 64 + ch0], w_hh[gate * 64 + ch0 + 1]);
    }
    frg[i] = val;
  }
  __syncthreads();
  int w = tid >> 6, lane = tid & 63, g = lane >> 4, m = lane & 15;
  int tile = blockIdx.x * 4 + w;
  if (tile >= NTILE) return;
  int n = tile * 16 + m;
  const f32x4 Z = {0.f, 0.f, 0.f, 0.f};
  float bhn[4][4];
#pragma unroll
  for (int mt = 0; mt < 4; ++mt)
#pragma unroll
    for (int r = 0; r < 4; ++r) bhn[mt][r] = b_hh[128 + mt * 16 + g * 4 + r];
  f32x4 Hc[4] = {Z, Z, Z, Z};
  u32 hb0[4] = {0u, 0u, 0u, 0u}, hb1[4] = {0u, 0u, 0u, 0u};
  const u32* sp = seqp + (size_t)tile * 3072;
  u32* hp = htile + (size_t)tile * 24 * 512;

  for (int t = 0; t < 24; ++t) {
    // opaque offset: compiler cannot prove frg reads loop-invariant -> no LICM hoist
    u32 fo = 0;
    asm volatile("" : "+v"(fo));
    const u32* fb = frg + fo;
    u32 sf0, sf1, sf2, sf3;
    if (g < 2) {
      sf0 = sp[(t * 8 + g * 4 + 0) * 16 + m];
      sf1 = sp[(t * 8 + g * 4 + 1) * 16 + m];
      sf2 = sp[(t * 8 + g * 4 + 2) * 16 + m];
      sf3 = sp[(t * 8 + g * 4 + 3) * 16 + m];
    } else if (g == 2) { sf0 = 0x00003f80u; sf1 = sf2 = sf3 = 0u; }
    else { sf0 = sf1 = sf2 = sf3 = 0u; }
    short8 sB  = mk4(sf0, sf1, sf2, sf3);
    short8 hB0 = mk4(hb0[0], hb0[1], hb0[2], hb0[3]);
    short8 hB1 = mk4(hb1[0], hb1[1], hb1[2], hb1[3]);
    // per output tile: compute r,z,n,ghn then consume — only 4 C-frags live
#pragma unroll
    for (int mt = 0; mt < 4; ++mt) {
      f32x4 Cr = mfma16(ldfrag(&fb[(mt * 64 + lane) * 4]), sB, Z);
      f32x4 Cz = mfma16(ldfrag(&fb[((4 + mt) * 64 + lane) * 4]), sB, Z);
      f32x4 Cn = mfma16(ldfrag(&fb[((8 + mt) * 64 + lane) * 4]), sB, Z);
      f32x4 Cghn = mfma16(ldfrag(&fb[((12 + (8 + mt) * 2) * 64 + lane) * 4]), hB0, Z);
      Cr = mfma16(ldfrag(&fb[((12 + mt * 2) * 64 + lane) * 4]), hB0, Cr);
      Cz = mfma16(ldfrag(&fb[((12 + (4 + mt) * 2) * 64 + lane) * 4]), hB0, Cz);
      Cghn = mfma16(ldfrag(&fb[((12 + (8 + mt) * 2 + 1) * 64 + lane) * 4]), hB1, Cghn);
      Cr = mfma16(ldfrag(&fb[((12 + mt * 2 + 1) * 64 + lane) * 4]), hB1, Cr);
      Cz = mfma16(ldfrag(&fb[((12 + (4 + mt) * 2 + 1) * 64 + lane) * 4]), hB1, Cz);
#pragma unroll
      for (int r = 0; r < 4; ++r) {
        float rr = sigm(Cr[r]);
        float zz = sigm(Cz[r]);
        float nn = tanh_f(Cn[r] + rr * (Cghn[r] + bhn[mt][r]));
        Hc[mt][r] = nn + zz * (Hc[mt][r] - nn);
      }
    }
    hb0[0] = cvtpk(Hc[0][0], Hc[0][1]); hb0[1] = cvtpk(Hc[0][2], Hc[0][3]);
    hb0[2] = cvtpk(Hc[1][0], Hc[1][1]); hb0[3] = cvtpk(Hc[1][2], Hc[1][3]);
    hb1[0] = cvtpk(Hc[2][0], Hc[2][1]); hb1[1] = cvtpk(Hc[2][2], Hc[2][3]);
    hb1[2] = cvtpk(Hc[3][0], Hc[3][1]); hb1[3] = cvtpk(Hc[3][2], Hc[3][3]);
    u32* op = hp + t * 512;
    *(uint2*)&op[(0 * 4 + g) * 32 + 2 * m] = make_uint2(hb0[0], hb0[1]);
    *(uint2*)&op[(1 * 4 + g) * 32 + 2 * m] = make_uint2(hb0[2], hb0[3]);
    *(uint2*)&op[(2 * 4 + g) * 32 + 2 * m] = make_uint2(hb1[0], hb1[1]);
    *(uint2*)&op[(3 * 4 + g) * 32 + 2 * m] = make_uint2(hb1[2], hb1[3]);
  }
#pragma unroll
  for (int mt = 0; mt < 4; ++mt)
    *(f32x4*)&h_last[(size_t)n * 64 + mt * 16 + g * 4] = Hc[mt];
}

// ============ K2: fold Wq/Wk/bq + scale into M (64x256) and abk (256) ============
__global__ void k_prep(const float* __restrict__ aw, const float* __restrict__ ab,
                       float* __restrict__ Mall, float* __restrict__ abk) {
  int j = threadIdx.x;
  int h = j >> 6, cp = j & 63;
  if (blockIdx.x < 64) {
    int c = blockIdx.x;
    float acc = 0.f;
    for (int d = 0; d < 16; ++d)
      acc += aw[(h * 16 + d) * 64 + c] * aw[(64 + h * 16 + d) * 64 + cp];
    Mall[c * 256 + j] = 0.25f * acc;
  } else {
    float acc = 0.f;
    for (int d = 0; d < 16; ++d)
      acc += ab[h * 16 + d] * aw[(64 + h * 16 + d) * 64 + cp];
    abk[j] = 0.25f * acc;
  }
}

// ============ K3: fused attention: U-MFMA + online scores/PV + V/out/proj MFMAs ============
__global__ __launch_bounds__(256, 2) void k_attn2(
    const u32* __restrict__ htile, const float* __restrict__ Mall,
    const float* __restrict__ abk, const float* __restrict__ aw,
    const float* __restrict__ ab, const float* __restrict__ out_w,
    const float* __restrict__ out_b, const float* __restrict__ proj_w,
    const float* __restrict__ proj_b, const float* __restrict__ h_last,
    const float* __restrict__ x, u32* __restrict__ xin_b) {
  __shared__ u32 mfrg[32 * 256];  // 32KB Mall frags
  __shared__ u32 vfrg[8 * 256];   // Wv
  __shared__ u32 ofrg[8 * 256];   // out_w
  __shared__ u32 pfrg[8 * 256];   // proj_w
  __shared__ float abks[256];
  __shared__ float smallb[192];   // out_b | proj_b | bv
  int tid = threadIdx.x;
  for (int i = tid; i < 32 * 256; i += 256) {
    int v = i & 3, lane = (i >> 2) & 63, f = i >> 8;
    int kt = f & 1, mt = f >> 1;
    int g = lane >> 4, mm = lane & 15;
    int jj = mt * 16 + mm, ch0 = CH0(kt, g, v);
    mfrg[i] = pack_bf(Mall[ch0 * 256 + jj], Mall[(ch0 + 1) * 256 + jj]);
  }
  for (int i = tid; i < 8 * 256; i += 256) {
    int v = i & 3, lane = (i >> 2) & 63, f = i >> 8;
    int kt = f & 1, mt = f >> 1;
    int g = lane >> 4, mm = lane & 15;
    int vo = mt * 16 + mm, ch0 = CH0(kt, g, v);
    vfrg[i] = pack_bf(aw[(128 + vo) * 64 + ch0], aw[(128 + vo) * 64 + ch0 + 1]);
    ofrg[i] = pack_bf(out_w[vo * 64 + ch0], out_w[vo * 64 + ch0 + 1]);
    pfrg[i] = pack_bf(proj_w[vo * 64 + ch0], proj_w[vo * 64 + ch0 + 1]);
  }
  if (tid < 256) abks[tid] = abk[tid];
  if (tid < 64) {
    smallb[tid] = out_b[tid];
    smallb[64 + tid] = proj_b[tid];
    smallb[128 + tid] = ab[128 + tid];
  }
  __syncthreads();
  int w = tid >> 6, lane = tid & 63, g = lane >> 4, m = lane & 15;
  int tile = blockIdx.x * 4 + w;
  if (tile >= NTILE) return;
  int n = tile * 16 + m;
  const f32x4 Z = {0.f, 0.f, 0.f, 0.f};
  const u32* hp = htile + (size_t)tile * 24 * 512;
  // h23 frags
  u32 h23d[2][4];
#pragma unroll
  for (int kt = 0; kt < 2; ++kt)
#pragma unroll
    for (int jh = 0; jh < 2; ++jh) {
      uint2 v = *(const uint2*)&hp[23 * 512 + ((kt * 2 + jh) * 4 + g) * 32 + 2 * m];
      h23d[kt][jh * 2] = v.x; h23d[kt][jh * 2 + 1] = v.y;
    }
  // U = Mall^T h23 + abk (C-layout: Uc[mt][r] = U[node m][mt*16+g*4+r])
  f32x4 Uc[16];
#pragma unroll
  for (int mt = 0; mt < 16; ++mt) Uc[mt] = *(const f32x4*)&abks[mt * 16 + g * 4];
#pragma unroll
  for (int mt = 0; mt < 16; ++mt)
#pragma unroll
    for (int kt = 0; kt < 2; ++kt)
      Uc[mt] = mfma16(ldfrag(&mfrg[((mt * 2 + kt) * 64 + lane) * 4]),
                      mk4(h23d[kt][0], h23d[kt][1], h23d[kt][2], h23d[kt][3]), Uc[mt]);
  // single pass over t: scores + exp + hbar (no-max softmax: |s| small, bounded)
  float den[4] = {0.f, 0.f, 0.f, 0.f};
  float hbar[4][4][4] = {};
  for (int t = 0; t < 24; ++t) {
    u32 hd[2][4];
#pragma unroll
    for (int kt = 0; kt < 2; ++kt)
#pragma unroll
      for (int jh = 0; jh < 2; ++jh) {
        uint2 v = *(const uint2*)&hp[t * 512 + ((kt * 2 + jh) * 4 + g) * 32 + 2 * m];
        hd[kt][jh * 2] = v.x; hd[kt][jh * 2 + 1] = v.y;
      }
    float hF[4][4];
#pragma unroll
    for (int kt = 0; kt < 2; ++kt)
#pragma unroll
      for (int jh = 0; jh < 2; ++jh)
#pragma unroll
        for (int jl = 0; jl < 2; ++jl) {
          u32 d = hd[kt][jh * 2 + jl];
          hF[kt * 2 + jh][jl * 2] = lo_f(d);
          hF[kt * 2 + jh][jl * 2 + 1] = hi_f(d);
        }
    float s[4];
#pragma unroll
    for (int h = 0; h < 4; ++h) {
      float acc = 0.f;
#pragma unroll
      for (int mt2 = 0; mt2 < 4; ++mt2)
#pragma unroll
        for (int r = 0; r < 4; ++r) acc += Uc[h * 4 + mt2][r] * hF[mt2][r];
      acc += __shfl_xor(acc, 16);
      acc += __shfl_xor(acc, 32);
      s[h] = acc;
    }
#pragma unroll
    for (int h = 0; h < 4; ++h) {
      float p = __expf(s[h]);
      den[h] += p;
#pragma unroll
      for (int mt2 = 0; mt2 < 4; ++mt2)
#pragma unroll
        for (int r = 0; r < 4; ++r) hbar[h][mt2][r] += p * hF[mt2][r];
    }
  }
  // o = Wv hbar / den + bv (per head)
  float oc[4][4];
#pragma unroll
  for (int h = 0; h < 4; ++h) {
    f32x4 C = Z;
#pragma unroll
    for (int kt = 0; kt < 2; ++kt) {
      short8 B = mk4(cvtpk(hbar[h][kt * 2][0], hbar[h][kt * 2][1]),
                     cvtpk(hbar[h][kt * 2][2], hbar[h][kt * 2][3]),
                     cvtpk(hbar[h][kt * 2 + 1][0], hbar[h][kt * 2 + 1][1]),
                     cvtpk(hbar[h][kt * 2 + 1][2], hbar[h][kt * 2 + 1][3]));
      C = mfma16(ldfrag(&vfrg[((h * 2 + kt) * 64 + lane) * 4]), B, C);
    }
    float inv = 1.f / den[h];
    f32x4 bv = *(const f32x4*)&smallb[128 + h * 16 + g * 4];
#pragma unroll
    for (int r = 0; r < 4; ++r) oc[h][r] = C[r] * inv + bv[r];
  }
  // al = out_w o + out_b
  f32x4 alc[4];
#pragma unroll
  for (int mt = 0; mt < 4; ++mt) alc[mt] = *(const f32x4*)&smallb[mt * 16 + g * 4];
#pragma unroll
  for (int kt = 0; kt < 2; ++kt) {
    short8 B = mk4(cvtpk(oc[kt * 2][0], oc[kt * 2][1]),
                   cvtpk(oc[kt * 2][2], oc[kt * 2][3]),
                   cvtpk(oc[kt * 2 + 1][0], oc[kt * 2 + 1][1]),
                   cvtpk(oc[kt * 2 + 1][2], oc[kt * 2 + 1][3]));
#pragma unroll
    for (int mt = 0; mt < 4; ++mt)
      alc[mt] = mfma16(ldfrag(&ofrg[((mt * 2 + kt) * 64 + lane) * 4]), B, alc[mt]);
  }
  // last = h23(fp32) + al ; te = proj_w last + proj_b
  float lc[4][4];
#pragma unroll
  for (int mt = 0; mt < 4; ++mt) {
    f32x4 hl = *(const f32x4*)&h_last[(size_t)n * 64 + mt * 16 + g * 4];
#pragma unroll
    for (int r = 0; r < 4; ++r) lc[mt][r] = hl[r] + alc[mt][r];
  }
  f32x4 tec[4];
#pragma unroll
  for (int mt = 0; mt < 4; ++mt) tec[mt] = *(const f32x4*)&smallb[64 + mt * 16 + g * 4];
#pragma unroll
  for (int kt = 0; kt < 2; ++kt) {
    short8 B = mk4(cvtpk(lc[kt * 2][0], lc[kt * 2][1]),
                   cvtpk(lc[kt * 2][2], lc[kt * 2][3]),
                   cvtpk(lc[kt * 2 + 1][0], lc[kt * 2 + 1][1]),
                   cvtpk(lc[kt * 2 + 1][2], lc[kt * 2 + 1][3]));
#pragma unroll
    for (int mt = 0; mt < 4; ++mt)
      tec[mt] = mfma16(ldfrag(&pfrg[((mt * 2 + kt) * 64 + lane) * 4]), B, tec[mt]);
  }
  // te -> xin_b dw 32..63: per-lane uint2 scatter (8B-aligned, no LDS transpose)
#pragma unroll
  for (int mt = 0; mt < 4; ++mt)
    *(uint2*)&xin_b[(size_t)n * 64 + 32 + mt * 8 + g * 2] =
        make_uint2(cvtpk(tec[mt][0], tec[mt][1]), cvtpk(tec[mt][2], tec[mt][3]));
  // x -> xin_b dw 0..31: direct coalesced conversion (lane (i2,q) owns node i2, block q)
  {
    int i2 = lane >> 2, q = lane & 3;
    int n2 = tile * 16 + i2;
#pragma unroll
    for (int j = 0; j < 2; ++j) {
      float4 x0 = ((const float4*)x)[(size_t)n2 * 16 + q * 4 + 2 * j];
      float4 x1 = ((const float4*)x)[(size_t)n2 * 16 + q * 4 + 2 * j + 1];
      uint4 vv;
      vv.x = cvtpk(x0.x, x0.y); vv.y = cvtpk(x0.z, x0.w);
      vv.z = cvtpk(x1.x, x1.y); vv.w = cvtpk(x1.z, x1.w);
      *(uint4*)&xin_b[(size_t)n2 * 64 + q * 8 + j * 4] = vv;
    }
  }
}

// ============ CSR construction ============
__global__ void k_zero(int* __restrict__ p, int n) {
  int i = blockIdx.x * 256 + threadIdx.x;
  if (i < n) p[i] = 0;
}
__global__ void k_count(const int* __restrict__ ei, int* __restrict__ rowptr) {
  int e = blockIdx.x * 256 + threadIdx.x;
  if (e >= ETOT) return;
  int d = (e < NEDGE) ? ei[NEDGE + e] : (e - NEDGE);
  atomicAdd(&rowptr[d + 1], 1);
}
__global__ void k_scan1(int* __restrict__ data, int* __restrict__ bsum, int n) {
  __shared__ int s[256];
  int i = blockIdx.x * 256 + threadIdx.x;
  s[threadIdx.x] = (i < n) ? data[i] : 0;
  __syncthreads();
  for (int off = 1; off < 256; off <<= 1) {
    int t = (threadIdx.x >= off) ? s[threadIdx.x - off] : 0;
    __syncthreads();
    s[threadIdx.x] += t;
    __syncthreads();
  }
  if (i < n) data[i] = s[threadIdx.x];
  if (threadIdx.x == 255) bsum[blockIdx.x] = s[255];
}
__global__ void k_scan2(int* __restrict__ bsum, int n) {
  __shared__ int s[256];
  int t = threadIdx.x;
  s[t] = (t < n) ? bsum[t] : 0;
  __syncthreads();
  for (int off = 1; off < 256; off <<= 1) {
    int v = (t >= off) ? s[t - off] : 0;
    __syncthreads();
    s[t] += v;
    __syncthreads();
  }
  if (t < n) bsum[t] = s[t];
}
__global__ void k_scan3(int* __restrict__ data, const int* __restrict__ bsum, int n) {
  int i = blockIdx.x * 256 + threadIdx.x;
  if (blockIdx.x > 0 && i < n) data[i] += bsum[blockIdx.x - 1];
}
__global__ void k_copycur(const int* __restrict__ rowptr, int* __restrict__ wcur, int n) {
  int i = blockIdx.x * 256 + threadIdx.x;
  if (i < n) wcur[i] = rowptr[i];
}
__global__ void k_scatter(const int* __restrict__ ei, int* __restrict__ wcur,
                          int* __restrict__ csr_src) {
  int e = blockIdx.x * 256 + threadIdx.x;
  if (e >= ETOT) return;
  int s = (e < NEDGE) ? ei[e] : (e - NEDGE);
  int d = (e < NEDGE) ? ei[NEDGE + e] : (e - NEDGE);
  int pos = atomicAdd(&wcur[d], 1);
  csr_src[pos] = s;
}

// ============ GAT transform (bf16 in/out) + fused attention logits ============
template <int KT>
__global__ __launch_bounds__(256, 2) void k_gat_gemm(
    const u32* __restrict__ A, const float* __restrict__ W,
    const float* __restrict__ at_s, const float* __restrict__ at_d,
    u32* __restrict__ Cout, float* __restrict__ as_out, float* __restrict__ ad_out) {
  __shared__ u32 frg[8 * KT * 256];
  int tid = threadIdx.x;
  int mt0 = blockIdx.y * 8;
  for (int i = tid; i < 8 * KT * 256; i += 256) {
    int v = i & 3, lane = (i >> 2) & 63, f = i >> 8;
    int kt = f % KT, mt = f / KT;
    int g = lane >> 4, mm = lane & 15;
    int o = (mt0 + mt) * 16 + mm;
    int ch0 = CH0(kt, g, v);
    frg[i] = pack_bf(W[ch0 * 256 + o], W[(ch0 + 1) * 256 + o]);
  }
  __syncthreads();
  int w = tid >> 6, lane = tid & 63, g = lane >> 4, m = lane & 15;
  int n0 = blockIdx.x * 128 + w * 32;
  const f32x4 Z = {0.f, 0.f, 0.f, 0.f};
  u32 bfr[2][KT][4];
#pragma unroll
  for (int nt = 0; nt < 2; ++nt) {
    int nn = n0 + nt * 16 + m;
    int nc = nn < N_NODES ? nn : N_NODES - 1;
#pragma unroll
    for (int kt = 0; kt < KT; ++kt)
#pragma unroll
      for (int jh = 0; jh < 2; ++jh) {
        uint2 uv = *(const uint2*)&A[(size_t)nc * (KT * 16) + (kt * 2 + jh) * 8 + g * 2];
        bfr[nt][kt][jh * 2] = uv.x; bfr[nt][kt][jh * 2 + 1] = uv.y;
      }
  }
  float ps[2][2] = {{0.f, 0.f}, {0.f, 0.f}};
  float pd[2][2] = {{0.f, 0.f}, {0.f, 0.f}};
#pragma unroll
  for (int mt = 0; mt < 8; ++mt) {
    f32x4 C[2] = {Z, Z};
#pragma unroll
    for (int kt = 0; kt < KT; ++kt) {
      short8 a = ldfrag(&frg[((mt * KT + kt) * 64 + lane) * 4]);
#pragma unroll
      for (int nt = 0; nt < 2; ++nt)
        C[nt] = mfma16(a, mk4(bfr[nt][kt][0], bfr[nt][kt][1], bfr[nt][kt][2], bfr[nt][kt][3]), C[nt]);
    }
    int j0 = (mt0 + mt) * 16 + g * 4;
    f32x4 as4 = *(const f32x4*)&at_s[j0];
    f32x4 ad4 = *(const f32x4*)&at_d[j0];
#pragma unroll
    for (int nt = 0; nt < 2; ++nt) {
      int nn = n0 + nt * 16 + m;
#pragma unroll
      for (int r = 0; r < 4; ++r) {
        ps[nt][mt >> 2] += C[nt][r] * as4[r];
        pd[nt][mt >> 2] += C[nt][r] * ad4[r];
      }
      if (nn < N_NODES)
        *(uint2*)&Cout[(size_t)nn * 128 + (mt0 + mt) * 8 + g * 2] =
            make_uint2(cvtpk(C[nt][0], C[nt][1]), cvtpk(C[nt][2], C[nt][3]));
    }
  }
#pragma unroll
  for (int nt = 0; nt < 2; ++nt)
#pragma unroll
    for (int hh = 0; hh < 2; ++hh) {
      float s = ps[nt][hh];
      s += __shfl_xor(s, 16); s += __shfl_xor(s, 32);
      float d = pd[nt][hh];
      d += __shfl_xor(d, 16); d += __shfl_xor(d, 32);
      int nn = n0 + nt * 16 + m;
      if (g == 0 && nn < N_NODES) {
        int h = blockIdx.y * 2 + hh;
        as_out[nn * 4 + h] = s;
        ad_out[nn * 4 + h] = d;
      }
    }
}

// ============ GAT1 aggregation: bf16 gather, bf16 out ============
__global__ __launch_bounds__(256) void k_gat_agg1(
    const u32* __restrict__ htb, const float* __restrict__ as_,
    const float* __restrict__ ad_, const int* __restrict__ rowptr,
    const int* __restrict__ csr_src, const float* __restrict__ bias,
    u32* __restrict__ h1b) {
  int w = threadIdx.x >> 6, lane = threadIdx.x & 63;
  int n = blockIdx.x * 4 + w;
  int hg = lane >> 4;
  float adh = ad_[n * 4 + hg];
  int beg = rowptr[n], end = rowptr[n + 1];
  float den = 0.f;
  float4 acc = {0.f, 0.f, 0.f, 0.f};
  for (int e = beg; e < end; ++e) {
    int s = csr_src[e];
    float ev = as_[s * 4 + hg] + adh;
    ev = ev > 0.f ? ev : 0.2f * ev;
    float p = __expf(ev);
    den += p;
    uint2 hv = ((const uint2*)htb)[(size_t)s * 64 + lane];
    acc.x += p * lo_f(hv.x); acc.y += p * hi_f(hv.x);
    acc.z += p * lo_f(hv.y); acc.w += p * hi_f(hv.y);
  }
  float inv = 1.f / den;
  float4 b4 = *(const float4*)&bias[lane * 4];
  float o0 = elu_f(acc.x * inv + b4.x);
  float o1 = elu_f(acc.y * inv + b4.y);
  float o2 = elu_f(acc.z * inv + b4.z);
  float o3 = elu_f(acc.w * inv + b4.w);
  ((uint2*)h1b)[(size_t)n * 64 + lane] = make_uint2(cvtpk(o0, o1), cvtpk(o2, o3));
}

// ============ GAT2 aggregation: bf16 gather, head-mean + elu + fused final linear ============
__global__ __launch_bounds__(256) void k_gat_agg2(
    const u32* __restrict__ htb, const float* __restrict__ as_,
    const float* __restrict__ ad_, const int* __restrict__ rowptr,
    const int* __restrict__ csr_src, const float* __restrict__ bias,
    const float* __restrict__ lin_w, const float* __restrict__ lin_b,
    float* __restrict__ out) {
  int w = threadIdx.x >> 6, lane = threadIdx.x & 63;
  int n = blockIdx.x * 4 + w;
  int hg = lane >> 4, q = lane & 15;
  float adh = ad_[n * 4 + hg];
  int beg = rowptr[n], end = rowptr[n + 1];
  float den = 0.f;
  float4 acc = {0.f, 0.f, 0.f, 0.f};
  for (int e = beg; e < end; ++e) {
    int s = csr_src[e];
    float ev = as_[s * 4 + hg] + adh;
    ev = ev > 0.f ? ev : 0.2f * ev;
    float p = __expf(ev);
    den += p;
    uint2 hv = ((const uint2*)htb)[(size_t)s * 64 + lane];
    acc.x += p * lo_f(hv.x); acc.y += p * hi_f(hv.x);
    acc.z += p * lo_f(hv.y); acc.w += p * hi_f(hv.y);
  }
  float inv = 1.f / den;
  float v0 = acc.x * inv, v1 = acc.y * inv, v2 = acc.z * inv, v3 = acc.w * inv;
  v0 += __shfl_xor(v0, 16); v0 += __shfl_xor(v0, 32);
  v1 += __shfl_xor(v1, 16); v1 += __shfl_xor(v1, 32);
  v2 += __shfl_xor(v2, 16); v2 += __shfl_xor(v2, 32);
  v3 += __shfl_xor(v3, 16); v3 += __shfl_xor(v3, 32);
  float4 b4 = *(const float4*)&bias[q * 4];
  float o0 = elu_f(v0 * 0.25f + b4.x);
  float o1 = elu_f(v1 * 0.25f + b4.y);
  float o2 = elu_f(v2 * 0.25f + b4.z);
  float o3 = elu_f(v3 * 0.25f + b4.w);
  float4 lw = *(const float4*)&lin_w[q * 4];
  float p2 = o0 * lw.x + o1 * lw.y + o2 * lw.z + o3 * lw.w;
  p2 += __shfl_xor(p2, 1); p2 += __shfl_xor(p2, 2);
  p2 += __shfl_xor(p2, 4); p2 += __shfl_xor(p2, 8);
  if (lane == 0) out[n] = p2 + lin_b[0];
}

extern "C" void kernel_launch(void* const* d_in, const int* in_sizes, int n_in,
                              void* d_out, int out_size, void* d_ws, size_t ws_size,
                              hipStream_t stream) {
  const float* x         = (const float*)d_in[0];
  const int*   ei        = (const int*)d_in[1];
  const float* seq       = (const float*)d_in[2];
  const float* gru_w_ih  = (const float*)d_in[3];
  const float* gru_w_hh  = (const float*)d_in[4];
  const float* gru_b_ih  = (const float*)d_in[5];
  const float* gru_b_hh  = (const float*)d_in[6];
  const float* attn_in_w = (const float*)d_in[7];
  const float* attn_in_b = (const float*)d_in[8];
  const float* attn_out_w= (const float*)d_in[9];
  const float* attn_out_b= (const float*)d_in[10];
  const float* proj_w    = (const float*)d_in[11];
  const float* proj_b    = (const float*)d_in[12];
  const float* gat1_w    = (const float*)d_in[13];
  const float* g1as      = (const float*)d_in[14];
  const float* g1ad      = (const float*)d_in[15];
  const float* gat1_b    = (const float*)d_in[16];
  const float* gat2_w    = (const float*)d_in[17];
  const float* g2as      = (const float*)d_in[18];
  const float* g2ad      = (const float*)d_in[19];
  const float* gat2_b    = (const float*)d_in[20];
  const float* lin_w     = (const float*)d_in[21];
  const float* lin_b     = (const float*)d_in[22];
  float* out = (float*)d_out;

  char* p = (char*)d_ws;
  auto alloc = [&](size_t bytes) {
    char* r = p;
    p += (bytes + 255) & ~(size_t)255;
    return r;
  };
  char*  region0 = alloc((size_t)NTILE * 24 * 512 * 4);     // 153.6MB: htile -> htb/h1b
  u32*   seqp    = (u32*)  alloc((size_t)NTILE * 3072 * 4); // 38.4MB
  float* h_last  = (float*)alloc((size_t)N_NODES * 64 * 4); // 12.8MB
  u32*   xin_b   = (u32*)  alloc((size_t)N_NODES * 64 * 4); // 12.8MB
  float* Mall    = (float*)alloc(64 * 256 * 4);
  float* abk     = (float*)alloc(256 * 4);
  float* a1s     = (float*)alloc((size_t)N_NODES * 4 * 4);
  float* a1d     = (float*)alloc((size_t)N_NODES * 4 * 4);
  float* a2s     = (float*)alloc((size_t)N_NODES * 4 * 4);
  float* a2d     = (float*)alloc((size_t)N_NODES * 4 * 4);
  int*   rowptr  = (int*)  alloc((size_t)(N_NODES + 1) * 4);
  int*   wcur    = (int*)  alloc((size_t)N_NODES * 4);
  int*   csr     = (int*)  alloc((size_t)ETOT * 4);
  int*   bsum    = (int*)  alloc(256 * 4);
  u32* htile = (u32*)region0;
  u32* htb   = (u32*)region0;                          // 25.6MB, after htile dead
  u32* h1b   = (u32*)(region0 + ((size_t)32 << 20));   // 25.6MB at +32MB

  // temporal encoder
  k_seqpack<<<NTILE, 128, 0, stream>>>(seq, seqp);
  k_gru<<<(NTILE + 3) / 4, 256, 0, stream>>>(seqp, gru_w_ih, gru_w_hh, gru_b_ih,
                                             gru_b_hh, htile, h_last);
  k_prep<<<65, 256, 0, stream>>>(attn_in_w, attn_in_b, Mall, abk);
  k_attn2<<<(NTILE + 3) / 4, 256, 0, stream>>>(htile, Mall, abk, attn_in_w, attn_in_b,
                                               attn_out_w, attn_out_b, proj_w, proj_b,
                                               h_last, x, xin_b);
  // CSR (dst-sorted), shared by both GAT layers
  k_zero<<<196, 256, 0, stream>>>(rowptr, N_NODES + 1);
  k_count<<<(ETOT + 255) / 256, 256, 0, stream>>>(ei, rowptr);
  k_scan1<<<196, 256, 0, stream>>>(rowptr, bsum, N_NODES + 1);
  k_scan2<<<1, 256, 0, stream>>>(bsum, 196);
  k_scan3<<<196, 256, 0, stream>>>(rowptr, bsum, N_NODES + 1);
  k_copycur<<<(N_NODES + 255) / 256, 256, 0, stream>>>(rowptr, wcur, N_NODES);
  k_scatter<<<(ETOT + 255) / 256, 256, 0, stream>>>(ei, wcur, csr);
  // GAT1 (concat + elu)
  k_gat_gemm<4><<<dim3(391, 2), 256, 0, stream>>>(xin_b, gat1_w, g1as, g1ad,
                                                  htb, a1s, a1d);
  k_gat_agg1<<<12500, 256, 0, stream>>>(htb, a1s, a1d, rowptr, csr, gat1_b, h1b);
  // GAT2 (mean + elu + final linear)
  k_gat_gemm<8><<<dim3(391, 2), 256, 0, stream>>>(h1b, gat2_w, g2as, g2ad,
                                                  htb, a2s, a2d);
  k_gat_agg2<<<12500, 256, 0, stream>>>(htb, a2s, a2d, rowptr, csr, gat2_b,
                                        lin_w, lin_b, out);
}